// Round 1
// baseline (432.820 us; speedup 1.0000x reference)
//
#include <hip/hip_runtime.h>

#define N_NODES 100000
#define N_EDGES 1600000
#define F 128
#define H 16
#define C 40
#define NH (N_NODES * H)
#define NB 391  // ceil(N_NODES / 256)

// ---------------- zero-fill (ws is poisoned 0xAA before every launch) -------
__global__ __launch_bounds__(256) void k_zero_i(int* __restrict__ p, int n) {
  int t = blockIdx.x * 256 + threadIdx.x;
  if (t < n) p[t] = 0;
}

// ---------------- CSR build: histogram of in-degree -------------------------
__global__ __launch_bounds__(256) void k_hist(const int* __restrict__ dst,
                                              int* __restrict__ A) {
  int t = blockIdx.x * 256 + threadIdx.x;
  if (t < N_EDGES) atomicAdd(&A[dst[t]], 1);
}

// ---------------- CSR build: 3-kernel exclusive scan over A[N_NODES] --------
__global__ __launch_bounds__(256) void k_scan1(const int* __restrict__ A,
                                               int* __restrict__ bsum) {
  __shared__ int ls[256];
  int tid = threadIdx.x;
  int t = blockIdx.x * 256 + tid;
  ls[tid] = (t < N_NODES) ? A[t] : 0;
  __syncthreads();
  for (int off = 128; off > 0; off >>= 1) {
    if (tid < off) ls[tid] += ls[tid + off];
    __syncthreads();
  }
  if (tid == 0) bsum[blockIdx.x] = ls[0];
}

__global__ __launch_bounds__(512) void k_scan2(int* __restrict__ bsum, int nb) {
  __shared__ int ls[512];
  int tid = threadIdx.x;
  int v = (tid < nb) ? bsum[tid] : 0;
  ls[tid] = v;
  __syncthreads();
  for (int off = 1; off < 512; off <<= 1) {
    int add = (tid >= off) ? ls[tid - off] : 0;
    __syncthreads();
    ls[tid] += add;
    __syncthreads();
  }
  if (tid < nb) bsum[tid] = ls[tid] - v;  // exclusive
}

__global__ __launch_bounds__(256) void k_scan3(int* __restrict__ A,
                                               const int* __restrict__ bsum) {
  __shared__ int ls[256];
  int tid = threadIdx.x;
  int t = blockIdx.x * 256 + tid;
  int v = (t < N_NODES) ? A[t] : 0;
  ls[tid] = v;
  __syncthreads();
  for (int off = 1; off < 256; off <<= 1) {
    int add = (tid >= off) ? ls[tid - off] : 0;
    __syncthreads();
    ls[tid] += add;
    __syncthreads();
  }
  if (t < N_NODES) A[t] = ls[tid] - v + bsum[blockIdx.x];  // exclusive start
}

// ---------------- CSR build: bucket fill (A becomes END offsets) ------------
__global__ __launch_bounds__(256) void k_fill(const int* __restrict__ src,
                                              const int* __restrict__ dst,
                                              int* __restrict__ A,
                                              int* __restrict__ srclist) {
  int t = blockIdx.x * 256 + threadIdx.x;
  if (t < N_EDGES) {
    int pos = atomicAdd(&A[dst[t]], 1);
    srclist[pos] = src[t];
  }
}

// ---------------- layer-1 projection: xn1 = x@Wn1, y1 = x@Ws1 + b1 ----------
// (unchanged from previous best) 64 nodes/block, 4 waves; wave w computes 8
// output cols; weight indices wave-uniform -> scalar loads.
__global__ __launch_bounds__(256) void k_proj1(
    const float* __restrict__ x, const float* __restrict__ wn,
    const float* __restrict__ wsf, const float* __restrict__ b,
    float* __restrict__ xn1, float* __restrict__ y1) {
  __shared__ float xs[64 * 129];
  const int tid = threadIdx.x;
  const int node0 = blockIdx.x * 64;
  for (int i = tid; i < 64 * 32; i += 256) {
    int r = i >> 5, cv = i & 31;
    int n = node0 + r;
    float4 v = make_float4(0.f, 0.f, 0.f, 0.f);
    if (n < N_NODES) v = ((const float4*)x)[(size_t)n * 32 + cv];
    float* dp = &xs[r * 129 + cv * 4];
    dp[0] = v.x; dp[1] = v.y; dp[2] = v.z; dp[3] = v.w;
  }
  __syncthreads();

  const int wave = __builtin_amdgcn_readfirstlane(tid >> 6);
  const int lane = tid & 63;
  const int n = node0 + lane;
  const float* wmat = (wave < 2) ? wn : wsf;
  const int c0 = (wave & 1) * 8;

  float acc[8] = {0.f, 0.f, 0.f, 0.f, 0.f, 0.f, 0.f, 0.f};
  const float* xrow = &xs[lane * 129];
#pragma unroll 8
  for (int k = 0; k < F; ++k) {
    float xv = xrow[k];
    const float* wr = wmat + k * H + c0;
#pragma unroll
    for (int j = 0; j < 8; ++j) acc[j] += xv * wr[j];
  }
  if (n < N_NODES) {
    if (wave < 2) {
#pragma unroll
      for (int j = 0; j < 8; ++j) xn1[n * H + c0 + j] = acc[j];
    } else {
#pragma unroll
      for (int j = 0; j < 8; ++j) y1[n * H + c0 + j] = acc[j] + b[c0 + j];
    }
  }
}

// ------- gather layer 1 + hidden fusion: h = relu(y1 + mean@..) in place ----
// One wave per node: 64 lanes = 4 edge slots x 16 features. Register
// accumulation, 2x shfl_xor reduce. No atomics.
__global__ __launch_bounds__(256) void k_gather1(const float* __restrict__ xn1,
                                                 const int* __restrict__ A,
                                                 const int* __restrict__ srclist,
                                                 float* __restrict__ y1h) {
  const int tid = threadIdx.x;
  const int wave = tid >> 6, lane = tid & 63;
  const int n = blockIdx.x * 4 + wave;
  if (n >= N_NODES) return;  // no __syncthreads in this kernel
  const int end = A[n];
  const int start = n ? A[n - 1] : 0;
  const int j = lane & 15, slot = lane >> 4;
  float acc = 0.f;
  for (int e = start + slot; e < end; e += 4) {
    int s = srclist[e];
    acc += xn1[s * H + j];
  }
  acc += __shfl_xor(acc, 16);
  acc += __shfl_xor(acc, 32);
  if (lane < 16) {
    float rd = 1.0f / fmaxf((float)(end - start), 1.0f);
    float v = y1h[n * H + j] + acc * rd;
    y1h[n * H + j] = fmaxf(v, 0.f);
  }
}

// ------- gather layer 2 + output fusion -------------------------------------
// One wave per node computes mean2 (registers), then 40 lanes produce
// out[n][:] = h@Ws2 + mean2@Wn2 + b2 with weights staged in LDS.
__global__ __launch_bounds__(256) void k_gather2_out(
    const float* __restrict__ h, const int* __restrict__ A,
    const int* __restrict__ srclist, const float* __restrict__ wn,
    const float* __restrict__ wsf, const float* __restrict__ b,
    float* __restrict__ out) {
  __shared__ float wn_s[H * C];
  __shared__ float ws_s[H * C];
  __shared__ float b_s[C];
  __shared__ float hv_s[4][H];
  __shared__ float mv_s[4][H];
  const int tid = threadIdx.x;
  for (int i = tid; i < H * C; i += 256) {
    wn_s[i] = wn[i];
    ws_s[i] = wsf[i];
  }
  if (tid < C) b_s[tid] = b[tid];

  const int wave = tid >> 6, lane = tid & 63;
  const int n = blockIdx.x * 4 + wave;
  const bool valid = (n < N_NODES);
  int start = 0, end = 0;
  if (valid) {
    end = A[n];
    start = n ? A[n - 1] : 0;
  }
  const int j = lane & 15, slot = lane >> 4;
  float acc = 0.f;
  for (int e = start + slot; e < end; e += 4) {
    int s = srclist[e];
    acc += h[s * H + j];
  }
  acc += __shfl_xor(acc, 16);
  acc += __shfl_xor(acc, 32);
  __syncthreads();  // weights staged; all waves reach this
  if (valid && lane < 16) {
    float rd = 1.0f / fmaxf((float)(end - start), 1.0f);
    mv_s[wave][j] = acc * rd;
    hv_s[wave][j] = h[n * H + j];
  }
  __syncthreads();
  if (valid && lane < C) {
    float o = b_s[lane];
#pragma unroll
    for (int jj = 0; jj < H; ++jj)
      o += hv_s[wave][jj] * ws_s[jj * C + lane] +
           mv_s[wave][jj] * wn_s[jj * C + lane];
    out[n * C + lane] = o;
  }
}

extern "C" void kernel_launch(void* const* d_in, const int* in_sizes, int n_in,
                              void* d_out, int out_size, void* d_ws,
                              size_t ws_size, hipStream_t stream) {
  const float* x = (const float*)d_in[0];
  const int* src = (const int*)d_in[1];
  const int* dst = (const int*)d_in[2];
  const float* wn1 = (const float*)d_in[3];
  const float* ws1 = (const float*)d_in[4];
  const float* b1 = (const float*)d_in[5];
  const float* wn2 = (const float*)d_in[6];
  const float* ws2 = (const float*)d_in[7];
  const float* b2 = (const float*)d_in[8];
  float* out = (float*)d_out;

  // xn1 lives in d_out's first NH floats (consumed by k_gather1 before
  // k_gather2_out writes d_out).
  float* xn1 = out;

  // ws layout (floats), 13.2 MB total — identical footprint to previous:
  //   [0, 100000)        A: deg counts -> exclusive starts -> end offsets (int)
  //   [100352, 100864)   bsum: per-block sums for scan (int)
  //   [102400, +E)       srclist: CSR edge sources (int)
  //   [102400+E, +NH)    y1h: y1 then h in place (float)
  float* wsp = (float*)d_ws;
  int* A = (int*)wsp;
  int* bsum = (int*)wsp + 100352;
  int* srclist = (int*)(wsp + 102400);
  float* y1h = wsp + 102400 + N_EDGES;

  k_zero_i<<<(N_NODES + 255) / 256, 256, 0, stream>>>(A, N_NODES);
  k_hist<<<(N_EDGES + 255) / 256, 256, 0, stream>>>(dst, A);
  k_scan1<<<NB, 256, 0, stream>>>(A, bsum);
  k_scan2<<<1, 512, 0, stream>>>(bsum, NB);
  k_scan3<<<NB, 256, 0, stream>>>(A, bsum);
  k_fill<<<(N_EDGES + 255) / 256, 256, 0, stream>>>(src, dst, A, srclist);
  k_proj1<<<(N_NODES + 63) / 64, 256, 0, stream>>>(x, wn1, ws1, b1, xn1, y1h);
  k_gather1<<<(N_NODES + 3) / 4, 256, 0, stream>>>(xn1, A, srclist, y1h);
  k_gather2_out<<<(N_NODES + 3) / 4, 256, 0, stream>>>(y1h, A, srclist, wn2,
                                                       ws2, b2, out);
}

// Round 4
// 353.320 us; speedup vs baseline: 1.2250x; 1.2250x over previous
//
#include <hip/hip_runtime.h>

#define N_NODES 100000
#define N_EDGES 1600000
#define F 128
#define H 16
#define C 40
#define NH (N_NODES * H)
#define NB 391      // ceil(N_NODES / 256)
#define RANGES 8    // = #XCDs; bid%8 ~ XCD id (perf heuristic only)
#define RNODES 12500  // N_NODES / RANGES
#define FILL_CHUNKS 256
#define FILL_PER 6250  // N_EDGES / FILL_CHUNKS

// ---------------- zero-fill (ws is poisoned 0xAA before every launch) -------
__global__ __launch_bounds__(256) void k_zero_i(int* __restrict__ p, int n) {
  int t = blockIdx.x * 256 + threadIdx.x;
  if (t < n) p[t] = 0;
}

// ---------------- CSR build: histogram of in-degree -------------------------
__global__ __launch_bounds__(256) void k_hist(const int* __restrict__ dst,
                                              int* __restrict__ A) {
  int t = blockIdx.x * 256 + threadIdx.x;
  if (t < N_EDGES) atomicAdd(&A[dst[t]], 1);
}

// ---------------- CSR build: 3-kernel exclusive scan over A[N_NODES] --------
__global__ __launch_bounds__(256) void k_scan1(const int* __restrict__ A,
                                               int* __restrict__ bsum) {
  __shared__ int ls[256];
  int tid = threadIdx.x;
  int t = blockIdx.x * 256 + tid;
  ls[tid] = (t < N_NODES) ? A[t] : 0;
  __syncthreads();
  for (int off = 128; off > 0; off >>= 1) {
    if (tid < off) ls[tid] += ls[tid + off];
    __syncthreads();
  }
  if (tid == 0) bsum[blockIdx.x] = ls[0];
}

__global__ __launch_bounds__(512) void k_scan2(int* __restrict__ bsum, int nb) {
  __shared__ int ls[512];
  int tid = threadIdx.x;
  int v = (tid < nb) ? bsum[tid] : 0;
  ls[tid] = v;
  __syncthreads();
  for (int off = 1; off < 512; off <<= 1) {
    int add = (tid >= off) ? ls[tid - off] : 0;
    __syncthreads();
    ls[tid] += add;
    __syncthreads();
  }
  if (tid < nb) bsum[tid] = ls[tid] - v;  // exclusive
}

__global__ __launch_bounds__(256) void k_scan3(int* __restrict__ A,
                                               const int* __restrict__ bsum) {
  __shared__ int ls[256];
  int tid = threadIdx.x;
  int t = blockIdx.x * 256 + tid;
  int v = (t < N_NODES) ? A[t] : 0;
  ls[tid] = v;
  __syncthreads();
  for (int off = 1; off < 256; off <<= 1) {
    int add = (tid >= off) ? ls[tid - off] : 0;
    __syncthreads();
    ls[tid] += add;
    __syncthreads();
  }
  if (t < N_NODES) A[t] = ls[tid] - v + bsum[blockIdx.x];  // exclusive start
}

// ---------------- CSR build: XCD-local bucket fill --------------------------
// Block (r = bid&7, chunk = bid>>3) scans one edge chunk but only handles
// dst in range r. With bid%8 ~ XCD id, all writers of srclist slice r sit on
// one XCD -> partial-line writes merge in its L2 (writeback ~6.4 MB full
// lines instead of ~102 MB masked partials). Correct under ANY placement.
// A becomes END offsets (same post-state as a plain fill).
__global__ __launch_bounds__(256) void k_fill_x(const int* __restrict__ src,
                                                const int* __restrict__ dst,
                                                int* __restrict__ A,
                                                int* __restrict__ srclist) {
  const int r = blockIdx.x & (RANGES - 1);
  const int chunk = blockIdx.x >> 3;
  const int lo = r * RNODES, hi = lo + RNODES;
  const int e0 = chunk * FILL_PER;
  const int e1 = e0 + FILL_PER;  // exact division
  for (int e = e0 + threadIdx.x; e < e1; e += 256) {
    int d = dst[e];
    if (d >= lo && d < hi) {
      int pos = atomicAdd(&A[d], 1);
      srclist[pos] = src[e];
    }
  }
}

// ---------------- layer-1 projection: xn1 = x@Wn1, y1 = x@Ws1 + b1 ----------
__global__ __launch_bounds__(256) void k_proj1(
    const float* __restrict__ x, const float* __restrict__ wn,
    const float* __restrict__ wsf, const float* __restrict__ b,
    float* __restrict__ xn1, float* __restrict__ y1) {
  __shared__ alignas(16) float xs[64 * 129];
  const int tid = threadIdx.x;
  const int node0 = blockIdx.x * 64;
  for (int i = tid; i < 64 * 32; i += 256) {
    int r = i >> 5, cv = i & 31;
    int n = node0 + r;
    float4 v = make_float4(0.f, 0.f, 0.f, 0.f);
    if (n < N_NODES) v = ((const float4*)x)[(size_t)n * 32 + cv];
    float* dp = &xs[r * 129 + cv * 4];
    dp[0] = v.x; dp[1] = v.y; dp[2] = v.z; dp[3] = v.w;
  }
  __syncthreads();

  const int wave = __builtin_amdgcn_readfirstlane(tid >> 6);
  const int lane = tid & 63;
  const int n = node0 + lane;
  const float* wmat = (wave < 2) ? wn : wsf;
  const int c0 = (wave & 1) * 8;

  float acc[8] = {0.f, 0.f, 0.f, 0.f, 0.f, 0.f, 0.f, 0.f};
  const float* xrow = &xs[lane * 129];
#pragma unroll 8
  for (int k = 0; k < F; ++k) {
    float xv = xrow[k];
    const float* wr = wmat + k * H + c0;
#pragma unroll
    for (int j = 0; j < 8; ++j) acc[j] += xv * wr[j];
  }
  if (n < N_NODES) {
    if (wave < 2) {
#pragma unroll
      for (int j = 0; j < 8; ++j) xn1[n * H + c0 + j] = acc[j];
    } else {
#pragma unroll
      for (int j = 0; j < 8; ++j) y1[n * H + c0 + j] = acc[j] + b[c0 + j];
    }
  }
}

// ------- gather layer 1 + hidden fusion: h = relu(y1 + mean@..) in place ----
// One wave per node: 16 edge slots x 4 lanes, float4 per lane. Avg degree 16
// -> ~1 iteration; 16 lines in flight per iteration (was 4, serial).
__global__ __launch_bounds__(256) void k_gather1(
    const float* __restrict__ xn1, const int* __restrict__ A,
    const int* __restrict__ srclist, float* __restrict__ y1h) {
  const int tid = threadIdx.x;
  const int wave = tid >> 6, lane = tid & 63;
  const int n = blockIdx.x * 4 + wave;
  if (n >= N_NODES) return;  // no __syncthreads in this kernel
  const int end = A[n];
  const int start = n ? A[n - 1] : 0;
  const int f4 = lane & 3, slot = lane >> 2;
  float4 acc = make_float4(0.f, 0.f, 0.f, 0.f);
  for (int e = start + slot; e < end; e += 16) {
    int s = srclist[e];
    float4 v = *(const float4*)&xn1[s * H + f4 * 4];
    acc.x += v.x; acc.y += v.y; acc.z += v.z; acc.w += v.w;
  }
#pragma unroll
  for (int m = 4; m <= 32; m <<= 1) {
    acc.x += __shfl_xor(acc.x, m);
    acc.y += __shfl_xor(acc.y, m);
    acc.z += __shfl_xor(acc.z, m);
    acc.w += __shfl_xor(acc.w, m);
  }
  if (lane < 4) {
    float rd = 1.0f / fmaxf((float)(end - start), 1.0f);
    float4 y = *(const float4*)&y1h[n * H + f4 * 4];
    float4 o;
    o.x = fmaxf(y.x + acc.x * rd, 0.f);
    o.y = fmaxf(y.y + acc.y * rd, 0.f);
    o.z = fmaxf(y.z + acc.z * rd, 0.f);
    o.w = fmaxf(y.w + acc.w * rd, 0.f);
    *(float4*)&y1h[n * H + f4 * 4] = o;
  }
}

// ------- gather layer 2 + output fusion -------------------------------------
__global__ __launch_bounds__(256) void k_gather2_out(
    const float* __restrict__ h, const int* __restrict__ A,
    const int* __restrict__ srclist, const float* __restrict__ wn,
    const float* __restrict__ wsf, const float* __restrict__ b,
    float* __restrict__ out) {
  __shared__ float wn_s[H * C];
  __shared__ float ws_s[H * C];
  __shared__ float b_s[C];
  __shared__ alignas(16) float hv_s[4][H];
  __shared__ alignas(16) float mv_s[4][H];
  const int tid = threadIdx.x;
  for (int i = tid; i < H * C; i += 256) {
    wn_s[i] = wn[i];
    ws_s[i] = wsf[i];
  }
  if (tid < C) b_s[tid] = b[tid];

  const int wave = tid >> 6, lane = tid & 63;
  const int n = blockIdx.x * 4 + wave;
  const bool valid = (n < N_NODES);
  int start = 0, end = 0;
  if (valid) {
    end = A[n];
    start = n ? A[n - 1] : 0;
  }
  const int f4 = lane & 3, slot = lane >> 2;
  float4 acc = make_float4(0.f, 0.f, 0.f, 0.f);
  for (int e = start + slot; e < end; e += 16) {
    int s = srclist[e];
    float4 v = *(const float4*)&h[s * H + f4 * 4];
    acc.x += v.x; acc.y += v.y; acc.z += v.z; acc.w += v.w;
  }
#pragma unroll
  for (int m = 4; m <= 32; m <<= 1) {
    acc.x += __shfl_xor(acc.x, m);
    acc.y += __shfl_xor(acc.y, m);
    acc.z += __shfl_xor(acc.z, m);
    acc.w += __shfl_xor(acc.w, m);
  }
  __syncthreads();  // weights staged; all waves reach this
  if (valid && lane < 4) {
    float rd = 1.0f / fmaxf((float)(end - start), 1.0f);
    float4 hv = *(const float4*)&h[n * H + f4 * 4];
    *(float4*)&hv_s[wave][f4 * 4] = hv;
    float4 mv;
    mv.x = acc.x * rd; mv.y = acc.y * rd; mv.z = acc.z * rd; mv.w = acc.w * rd;
    *(float4*)&mv_s[wave][f4 * 4] = mv;
  }
  __syncthreads();
  if (valid && lane < C) {
    float o = b_s[lane];
#pragma unroll
    for (int jj = 0; jj < H; ++jj)
      o += hv_s[wave][jj] * ws_s[jj * C + lane] +
           mv_s[wave][jj] * wn_s[jj * C + lane];
    out[n * C + lane] = o;
  }
}

extern "C" void kernel_launch(void* const* d_in, const int* in_sizes, int n_in,
                              void* d_out, int out_size, void* d_ws,
                              size_t ws_size, hipStream_t stream) {
  const float* x = (const float*)d_in[0];
  const int* src = (const int*)d_in[1];
  const int* dst = (const int*)d_in[2];
  const float* wn1 = (const float*)d_in[3];
  const float* ws1 = (const float*)d_in[4];
  const float* b1 = (const float*)d_in[5];
  const float* wn2 = (const float*)d_in[6];
  const float* ws2 = (const float*)d_in[7];
  const float* b2 = (const float*)d_in[8];
  float* out = (float*)d_out;

  // xn1 lives in d_out's first NH floats (consumed by k_gather1 before
  // k_gather2_out writes d_out).
  float* xn1 = out;

  // ws layout (floats), 13.2 MB total:
  //   [0, 100000)        A: deg counts -> exclusive starts -> end offsets (int)
  //   [100352, 100864)   bsum: per-block sums for scan (int)
  //   [102400, +E)       srclist: CSR edge sources (int)
  //   [102400+E, +NH)    y1h: y1 then h in place (float)
  float* wsp = (float*)d_ws;
  int* A = (int*)wsp;
  int* bsum = (int*)wsp + 100352;
  int* srclist = (int*)(wsp + 102400);
  float* y1h = wsp + 102400 + N_EDGES;

  k_zero_i<<<(N_NODES + 255) / 256, 256, 0, stream>>>(A, N_NODES);
  k_hist<<<(N_EDGES + 255) / 256, 256, 0, stream>>>(dst, A);
  k_scan1<<<NB, 256, 0, stream>>>(A, bsum);
  k_scan2<<<1, 512, 0, stream>>>(bsum, NB);
  k_scan3<<<NB, 256, 0, stream>>>(A, bsum);
  k_fill_x<<<RANGES * FILL_CHUNKS, 256, 0, stream>>>(src, dst, A, srclist);
  k_proj1<<<(N_NODES + 63) / 64, 256, 0, stream>>>(x, wn1, ws1, b1, xn1, y1h);
  k_gather1<<<(N_NODES + 3) / 4, 256, 0, stream>>>(xn1, A, srclist, y1h);
  k_gather2_out<<<(N_NODES + 3) / 4, 256, 0, stream>>>(y1h, A, srclist, wn2,
                                                       ws2, b2, out);
}

// Round 5
// 255.481 us; speedup vs baseline: 1.6941x; 1.3830x over previous
//
#include <hip/hip_runtime.h>

#define N_NODES 100000
#define N_EDGES 1600000
#define F 128
#define H 16
#define C 40
#define NH (N_NODES * H)
#define NBKT 391   // buckets of 256 nodes: ceil(100000/256)
#define ABLK 256   // partition blocks
#define EPB 6250   // edges per partition block (256*6250 = 1.6M exact)
#define CAP 6144   // per-bucket LDS capacity (mean 4096, ~32 sigma headroom)

// ---------------- zero-fill (ws is poisoned 0xAA before every launch) -------
__global__ __launch_bounds__(256) void k_zero_i(int* __restrict__ p, int n) {
  int t = blockIdx.x * 256 + threadIdx.x;
  if (t < n) p[t] = 0;
}

// ---------------- bucket counts: LDS hist -> <=391 global atomics/block -----
__global__ __launch_bounds__(256) void k_bcount(const int* __restrict__ dst,
                                                int* __restrict__ counts) {
  __shared__ int cnt[NBKT];
  for (int i = threadIdx.x; i < NBKT; i += 256) cnt[i] = 0;
  __syncthreads();
  const int e0 = blockIdx.x * EPB;
  for (int e = e0 + threadIdx.x; e < e0 + EPB; e += 256)
    atomicAdd(&cnt[dst[e] >> 8], 1);
  __syncthreads();
  for (int i = threadIdx.x; i < NBKT; i += 256)
    if (cnt[i]) atomicAdd(&counts[i], cnt[i]);
}

// ---------------- scan 391 bucket counts -> starts (excl) + cursors copy ----
__global__ __launch_bounds__(512) void k_bscan(const int* __restrict__ counts,
                                               int* __restrict__ starts,
                                               int* __restrict__ cursors) {
  __shared__ int ls[512];
  int tid = threadIdx.x;
  int v = (tid < NBKT) ? counts[tid] : 0;
  ls[tid] = v;
  __syncthreads();
  for (int off = 1; off < 512; off <<= 1) {
    int a = (tid >= off) ? ls[tid - off] : 0;
    __syncthreads();
    ls[tid] += a;
    __syncthreads();
  }
  if (tid < NBKT) {
    int ex = ls[tid] - v;
    starts[tid] = ex;
    cursors[tid] = ex;
  }
}

// ---------------- bucket fill: packed pairs, contiguous per block-bucket ----
// pair = (dlocal<<17) | src  (dlocal<256 -> 8 bits; src<100000 -> 17 bits)
__global__ __launch_bounds__(256) void k_bfill(const int* __restrict__ src,
                                               const int* __restrict__ dst,
                                               int* __restrict__ cursors,
                                               int* __restrict__ P) {
  __shared__ int cnt[NBKT];
  __shared__ int base[NBKT];
  __shared__ int cur[NBKT];
  for (int i = threadIdx.x; i < NBKT; i += 256) {
    cnt[i] = 0;
    cur[i] = 0;
  }
  __syncthreads();
  const int e0 = blockIdx.x * EPB;
  for (int e = e0 + threadIdx.x; e < e0 + EPB; e += 256)
    atomicAdd(&cnt[dst[e] >> 8], 1);
  __syncthreads();
  for (int i = threadIdx.x; i < NBKT; i += 256)
    if (cnt[i]) base[i] = atomicAdd(&cursors[i], cnt[i]);
  __syncthreads();
  for (int e = e0 + threadIdx.x; e < e0 + EPB; e += 256) {
    int d = dst[e], s = src[e];
    int b = d >> 8;
    int off = atomicAdd(&cur[b], 1);
    P[base[b] + off] = ((d & 255) << 17) | s;
  }
}

// ---------------- per-bucket CSR: sort pairs by dlocal entirely in LDS ------
// Rewrites P[st..st+cnt) in place as srclist (src ints ordered by dst), and
// writes A[node] = global end offset. All global IO is dense full lines.
__global__ __launch_bounds__(256) void k_bcsr(const int* __restrict__ counts,
                                              const int* __restrict__ starts,
                                              int* __restrict__ P,
                                              int* __restrict__ A) {
  __shared__ int pbuf[CAP];
  __shared__ int sbuf[CAP];
  __shared__ int h[256];
  __shared__ int cur[256];
  const int b = blockIdx.x, tid = threadIdx.x;
  const int st = starts[b];
  int cnt = counts[b];
  if (cnt > CAP) cnt = CAP;  // ~impossible; guards LDS
  for (int i = tid; i < cnt; i += 256) pbuf[i] = P[st + i];
  h[tid] = 0;
  __syncthreads();
  for (int i = tid; i < cnt; i += 256) atomicAdd(&h[pbuf[i] >> 17], 1);
  __syncthreads();
  int v = h[tid];
  // inclusive scan of h (Hillis-Steele)
  for (int off = 1; off < 256; off <<= 1) {
    int a = (tid >= off) ? h[tid - off] : 0;
    __syncthreads();
    h[tid] += a;
    __syncthreads();
  }
  int incl = h[tid];
  cur[tid] = incl - v;  // exclusive
  int node = b * 256 + tid;
  if (node < N_NODES) A[node] = st + incl;
  __syncthreads();
  for (int i = tid; i < cnt; i += 256) {
    int pv = pbuf[i];
    int nl = pv >> 17;
    int p = atomicAdd(&cur[nl], 1);
    sbuf[p] = pv & 0x1FFFF;
  }
  __syncthreads();
  for (int i = tid; i < cnt; i += 256) P[st + i] = sbuf[i];
}

// ---------------- layer-1 projection: xn1 = x@Wn1, y1 = x@Ws1 + b1 ----------
__global__ __launch_bounds__(256) void k_proj1(
    const float* __restrict__ x, const float* __restrict__ wn,
    const float* __restrict__ wsf, const float* __restrict__ b,
    float* __restrict__ xn1, float* __restrict__ y1) {
  __shared__ alignas(16) float xs[64 * 129];
  const int tid = threadIdx.x;
  const int node0 = blockIdx.x * 64;
  for (int i = tid; i < 64 * 32; i += 256) {
    int r = i >> 5, cv = i & 31;
    int n = node0 + r;
    float4 v = make_float4(0.f, 0.f, 0.f, 0.f);
    if (n < N_NODES) v = ((const float4*)x)[(size_t)n * 32 + cv];
    float* dp = &xs[r * 129 + cv * 4];
    dp[0] = v.x; dp[1] = v.y; dp[2] = v.z; dp[3] = v.w;
  }
  __syncthreads();

  const int wave = __builtin_amdgcn_readfirstlane(tid >> 6);
  const int lane = tid & 63;
  const int n = node0 + lane;
  const float* wmat = (wave < 2) ? wn : wsf;
  const int c0 = (wave & 1) * 8;

  float acc[8] = {0.f, 0.f, 0.f, 0.f, 0.f, 0.f, 0.f, 0.f};
  const float* xrow = &xs[lane * 129];
#pragma unroll 8
  for (int k = 0; k < F; ++k) {
    float xv = xrow[k];
    const float* wr = wmat + k * H + c0;
#pragma unroll
    for (int j = 0; j < 8; ++j) acc[j] += xv * wr[j];
  }
  if (n < N_NODES) {
    if (wave < 2) {
#pragma unroll
      for (int j = 0; j < 8; ++j) xn1[n * H + c0 + j] = acc[j];
    } else {
#pragma unroll
      for (int j = 0; j < 8; ++j) y1[n * H + c0 + j] = acc[j] + b[c0 + j];
    }
  }
}

// ------- gather layer 1 + hidden fusion: h = relu(y1 + mean@..) in place ----
__global__ __launch_bounds__(256) void k_gather1(
    const float* __restrict__ xn1, const int* __restrict__ A,
    const int* __restrict__ srclist, float* __restrict__ y1h) {
  const int tid = threadIdx.x;
  const int wave = tid >> 6, lane = tid & 63;
  const int n = blockIdx.x * 4 + wave;
  if (n >= N_NODES) return;  // no __syncthreads in this kernel
  const int end = A[n];
  const int start = n ? A[n - 1] : 0;
  const int f4 = lane & 3, slot = lane >> 2;
  float4 acc = make_float4(0.f, 0.f, 0.f, 0.f);
  for (int e = start + slot; e < end; e += 16) {
    int s = srclist[e];
    float4 v = *(const float4*)&xn1[s * H + f4 * 4];
    acc.x += v.x; acc.y += v.y; acc.z += v.z; acc.w += v.w;
  }
#pragma unroll
  for (int m = 4; m <= 32; m <<= 1) {
    acc.x += __shfl_xor(acc.x, m);
    acc.y += __shfl_xor(acc.y, m);
    acc.z += __shfl_xor(acc.z, m);
    acc.w += __shfl_xor(acc.w, m);
  }
  if (lane < 4) {
    float rd = 1.0f / fmaxf((float)(end - start), 1.0f);
    float4 y = *(const float4*)&y1h[n * H + f4 * 4];
    float4 o;
    o.x = fmaxf(y.x + acc.x * rd, 0.f);
    o.y = fmaxf(y.y + acc.y * rd, 0.f);
    o.z = fmaxf(y.z + acc.z * rd, 0.f);
    o.w = fmaxf(y.w + acc.w * rd, 0.f);
    *(float4*)&y1h[n * H + f4 * 4] = o;
  }
}

// ------- gather layer 2 + output fusion -------------------------------------
__global__ __launch_bounds__(256) void k_gather2_out(
    const float* __restrict__ h, const int* __restrict__ A,
    const int* __restrict__ srclist, const float* __restrict__ wn,
    const float* __restrict__ wsf, const float* __restrict__ b,
    float* __restrict__ out) {
  __shared__ float wn_s[H * C];
  __shared__ float ws_s[H * C];
  __shared__ float b_s[C];
  __shared__ alignas(16) float hv_s[4][H];
  __shared__ alignas(16) float mv_s[4][H];
  const int tid = threadIdx.x;
  for (int i = tid; i < H * C; i += 256) {
    wn_s[i] = wn[i];
    ws_s[i] = wsf[i];
  }
  if (tid < C) b_s[tid] = b[tid];

  const int wave = tid >> 6, lane = tid & 63;
  const int n = blockIdx.x * 4 + wave;
  const bool valid = (n < N_NODES);
  int start = 0, end = 0;
  if (valid) {
    end = A[n];
    start = n ? A[n - 1] : 0;
  }
  const int f4 = lane & 3, slot = lane >> 2;
  float4 acc = make_float4(0.f, 0.f, 0.f, 0.f);
  for (int e = start + slot; e < end; e += 16) {
    int s = srclist[e];
    float4 v = *(const float4*)&h[s * H + f4 * 4];
    acc.x += v.x; acc.y += v.y; acc.z += v.z; acc.w += v.w;
  }
#pragma unroll
  for (int m = 4; m <= 32; m <<= 1) {
    acc.x += __shfl_xor(acc.x, m);
    acc.y += __shfl_xor(acc.y, m);
    acc.z += __shfl_xor(acc.z, m);
    acc.w += __shfl_xor(acc.w, m);
  }
  __syncthreads();  // weights staged; all waves reach this
  if (valid && lane < 4) {
    float rd = 1.0f / fmaxf((float)(end - start), 1.0f);
    float4 hv = *(const float4*)&h[n * H + f4 * 4];
    *(float4*)&hv_s[wave][f4 * 4] = hv;
    float4 mv;
    mv.x = acc.x * rd; mv.y = acc.y * rd; mv.z = acc.z * rd; mv.w = acc.w * rd;
    *(float4*)&mv_s[wave][f4 * 4] = mv;
  }
  __syncthreads();
  if (valid && lane < C) {
    float o = b_s[lane];
#pragma unroll
    for (int jj = 0; jj < H; ++jj)
      o += hv_s[wave][jj] * ws_s[jj * C + lane] +
           mv_s[wave][jj] * wn_s[jj * C + lane];
    out[n * C + lane] = o;
  }
}

extern "C" void kernel_launch(void* const* d_in, const int* in_sizes, int n_in,
                              void* d_out, int out_size, void* d_ws,
                              size_t ws_size, hipStream_t stream) {
  const float* x = (const float*)d_in[0];
  const int* src = (const int*)d_in[1];
  const int* dst = (const int*)d_in[2];
  const float* wn1 = (const float*)d_in[3];
  const float* ws1 = (const float*)d_in[4];
  const float* b1 = (const float*)d_in[5];
  const float* wn2 = (const float*)d_in[6];
  const float* ws2 = (const float*)d_in[7];
  const float* b2 = (const float*)d_in[8];
  float* out = (float*)d_out;

  // xn1 lives in d_out's first NH floats (consumed by k_gather1 before
  // k_gather2_out writes d_out).
  float* xn1 = out;

  // ws layout (ints/floats), 13.2 MB total (identical size to prior rounds):
  //   [0, 100000)          A: CSR end offsets (int)
  //   [100000, 100391)     counts: per-bucket edge counts (int)
  //   [100391, 100782)     starts: per-bucket exclusive starts (int)
  //   [100782, 101173)     cursors: fill cursors (int)
  //   [102400, +E)         P: packed pairs -> srclist in place (int)
  //   [102400+E, +NH)      y1h: y1 then h in place (float)
  float* wsp = (float*)d_ws;
  int* A = (int*)wsp;
  int* counts = (int*)wsp + 100000;
  int* starts = (int*)wsp + 100391;
  int* cursors = (int*)wsp + 100782;
  int* P = (int*)(wsp + 102400);
  float* y1h = wsp + 102400 + N_EDGES;

  k_zero_i<<<2, 256, 0, stream>>>(counts, NBKT);
  k_bcount<<<ABLK, 256, 0, stream>>>(dst, counts);
  k_bscan<<<1, 512, 0, stream>>>(counts, starts, cursors);
  k_bfill<<<ABLK, 256, 0, stream>>>(src, dst, cursors, P);
  k_bcsr<<<NBKT, 256, 0, stream>>>(counts, starts, P, A);
  k_proj1<<<(N_NODES + 63) / 64, 256, 0, stream>>>(x, wn1, ws1, b1, xn1, y1h);
  k_gather1<<<(N_NODES + 3) / 4, 256, 0, stream>>>(xn1, A, P, y1h);
  k_gather2_out<<<(N_NODES + 3) / 4, 256, 0, stream>>>(y1h, A, P, wn2, ws2, b2,
                                                       out);
}

// Round 6
// 247.106 us; speedup vs baseline: 1.7516x; 1.0339x over previous
//
#include <hip/hip_runtime.h>
#include <hip/hip_fp16.h>

#define N_NODES 100000
#define N_EDGES 1600000
#define F 128
#define H 16
#define C 40
#define NH (N_NODES * H)
#define NBKT 391   // buckets of 256 nodes: ceil(100000/256)
#define ABLK 256   // partition blocks
#define EPB 6250   // edges per partition block (256*6250 = 1.6M exact)
#define CAP 6144   // per-bucket LDS capacity (mean 4096, ~32 sigma headroom)

// ---------------- zero-fill (ws is poisoned 0xAA before every launch) -------
__global__ __launch_bounds__(256) void k_zero_i(int* __restrict__ p, int n) {
  int t = blockIdx.x * 256 + threadIdx.x;
  if (t < n) p[t] = 0;
}

// ---------------- bucket counts: LDS hist -> <=391 global atomics/block -----
__global__ __launch_bounds__(256) void k_bcount(const int* __restrict__ dst,
                                                int* __restrict__ counts) {
  __shared__ int cnt[NBKT];
  for (int i = threadIdx.x; i < NBKT; i += 256) cnt[i] = 0;
  __syncthreads();
  const int e0 = blockIdx.x * EPB;
  for (int e = e0 + threadIdx.x; e < e0 + EPB; e += 256)
    atomicAdd(&cnt[dst[e] >> 8], 1);
  __syncthreads();
  for (int i = threadIdx.x; i < NBKT; i += 256)
    if (cnt[i]) atomicAdd(&counts[i], cnt[i]);
}

// ---------------- scan 391 bucket counts -> starts (excl) + cursors copy ----
__global__ __launch_bounds__(512) void k_bscan(const int* __restrict__ counts,
                                               int* __restrict__ starts,
                                               int* __restrict__ cursors) {
  __shared__ int ls[512];
  int tid = threadIdx.x;
  int v = (tid < NBKT) ? counts[tid] : 0;
  ls[tid] = v;
  __syncthreads();
  for (int off = 1; off < 512; off <<= 1) {
    int a = (tid >= off) ? ls[tid - off] : 0;
    __syncthreads();
    ls[tid] += a;
    __syncthreads();
  }
  if (tid < NBKT) {
    int ex = ls[tid] - v;
    starts[tid] = ex;
    cursors[tid] = ex;
  }
}

// ---------------- bucket fill: packed pairs, contiguous per block-bucket ----
// pair = (dlocal<<17) | src  (dlocal<256 -> 8 bits; src<100000 -> 17 bits)
__global__ __launch_bounds__(256) void k_bfill(const int* __restrict__ src,
                                               const int* __restrict__ dst,
                                               int* __restrict__ cursors,
                                               int* __restrict__ P) {
  __shared__ int cnt[NBKT];
  __shared__ int base[NBKT];
  __shared__ int cur[NBKT];
  for (int i = threadIdx.x; i < NBKT; i += 256) {
    cnt[i] = 0;
    cur[i] = 0;
  }
  __syncthreads();
  const int e0 = blockIdx.x * EPB;
  for (int e = e0 + threadIdx.x; e < e0 + EPB; e += 256)
    atomicAdd(&cnt[dst[e] >> 8], 1);
  __syncthreads();
  for (int i = threadIdx.x; i < NBKT; i += 256)
    if (cnt[i]) base[i] = atomicAdd(&cursors[i], cnt[i]);
  __syncthreads();
  for (int e = e0 + threadIdx.x; e < e0 + EPB; e += 256) {
    int d = dst[e], s = src[e];
    int b = d >> 8;
    int off = atomicAdd(&cur[b], 1);
    P[base[b] + off] = ((d & 255) << 17) | s;
  }
}

// ---------------- per-bucket CSR: sort pairs by dlocal entirely in LDS ------
__global__ __launch_bounds__(256) void k_bcsr(const int* __restrict__ counts,
                                              const int* __restrict__ starts,
                                              int* __restrict__ P,
                                              int* __restrict__ A) {
  __shared__ int pbuf[CAP];
  __shared__ int sbuf[CAP];
  __shared__ int h[256];
  __shared__ int cur[256];
  const int b = blockIdx.x, tid = threadIdx.x;
  const int st = starts[b];
  int cnt = counts[b];
  if (cnt > CAP) cnt = CAP;  // ~impossible; guards LDS
  for (int i = tid; i < cnt; i += 256) pbuf[i] = P[st + i];
  h[tid] = 0;
  __syncthreads();
  for (int i = tid; i < cnt; i += 256) atomicAdd(&h[pbuf[i] >> 17], 1);
  __syncthreads();
  int v = h[tid];
  for (int off = 1; off < 256; off <<= 1) {
    int a = (tid >= off) ? h[tid - off] : 0;
    __syncthreads();
    h[tid] += a;
    __syncthreads();
  }
  int incl = h[tid];
  cur[tid] = incl - v;  // exclusive
  int node = b * 256 + tid;
  if (node < N_NODES) A[node] = st + incl;
  __syncthreads();
  for (int i = tid; i < cnt; i += 256) {
    int pv = pbuf[i];
    int nl = pv >> 17;
    int p = atomicAdd(&cur[nl], 1);
    sbuf[p] = pv & 0x1FFFF;
  }
  __syncthreads();
  for (int i = tid; i < cnt; i += 256) P[st + i] = sbuf[i];
}

// ---------------- layer-1 projection: xn1 = x@Wn1, y1 = x@Ws1 + b1 (fp16) ---
__global__ __launch_bounds__(256) void k_proj1(
    const float* __restrict__ x, const float* __restrict__ wn,
    const float* __restrict__ wsf, const float* __restrict__ b,
    __half* __restrict__ xn1h, __half* __restrict__ y1h16) {
  __shared__ alignas(16) float xs[64 * 129];
  const int tid = threadIdx.x;
  const int node0 = blockIdx.x * 64;
  for (int i = tid; i < 64 * 32; i += 256) {
    int r = i >> 5, cv = i & 31;
    int n = node0 + r;
    float4 v = make_float4(0.f, 0.f, 0.f, 0.f);
    if (n < N_NODES) v = ((const float4*)x)[(size_t)n * 32 + cv];
    float* dp = &xs[r * 129 + cv * 4];
    dp[0] = v.x; dp[1] = v.y; dp[2] = v.z; dp[3] = v.w;
  }
  __syncthreads();

  const int wave = __builtin_amdgcn_readfirstlane(tid >> 6);
  const int lane = tid & 63;
  const int n = node0 + lane;
  const float* wmat = (wave < 2) ? wn : wsf;
  const int c0 = (wave & 1) * 8;

  float acc[8] = {0.f, 0.f, 0.f, 0.f, 0.f, 0.f, 0.f, 0.f};
  const float* xrow = &xs[lane * 129];
#pragma unroll 8
  for (int k = 0; k < F; ++k) {
    float xv = xrow[k];
    const float* wr = wmat + k * H + c0;
#pragma unroll
    for (int j = 0; j < 8; ++j) acc[j] += xv * wr[j];
  }
  if (n < N_NODES) {
    union { ushort u[8]; uint4 v; } pk;
    if (wave < 2) {
#pragma unroll
      for (int j = 0; j < 8; ++j)
        pk.u[j] = __half_as_ushort(__float2half(acc[j]));
      *(uint4*)&xn1h[n * H + c0] = pk.v;   // byte 32n+2c0, 16B aligned
    } else {
#pragma unroll
      for (int j = 0; j < 8; ++j)
        pk.u[j] = __half_as_ushort(__float2half(acc[j] + b[c0 + j]));
      *(uint4*)&y1h16[n * H + c0] = pk.v;
    }
  }
}

// ------- gather layer 1 + hidden fusion: h16 = relu(y1 + mean) --------------
// One wave per node: 16 edge slots x 4 lanes, 8B (4 halves) per lane. fp16
// source rows (32B) keep the 3.2MB array L2-resident; accumulate in f32.
__global__ __launch_bounds__(256) void k_gather1(
    const __half* __restrict__ xn1h, const int* __restrict__ A,
    const int* __restrict__ srclist, const __half* __restrict__ y1h16,
    __half* __restrict__ h16) {
  const int tid = threadIdx.x;
  const int wave = tid >> 6, lane = tid & 63;
  const int n = blockIdx.x * 4 + wave;
  if (n >= N_NODES) return;  // no __syncthreads in this kernel
  const int end = A[n];
  const int start = n ? A[n - 1] : 0;
  const int f4 = lane & 3, slot = lane >> 2;
  float4 acc = make_float4(0.f, 0.f, 0.f, 0.f);
  const ushort4* xr = (const ushort4*)xn1h;  // one ushort4 = 4 halves = 8B
  for (int e = start + slot; e < end; e += 16) {
    int s = srclist[e];
    ushort4 q = xr[s * 4 + f4];
    acc.x += __half2float(__ushort_as_half(q.x));
    acc.y += __half2float(__ushort_as_half(q.y));
    acc.z += __half2float(__ushort_as_half(q.z));
    acc.w += __half2float(__ushort_as_half(q.w));
  }
#pragma unroll
  for (int m = 4; m <= 32; m <<= 1) {
    acc.x += __shfl_xor(acc.x, m);
    acc.y += __shfl_xor(acc.y, m);
    acc.z += __shfl_xor(acc.z, m);
    acc.w += __shfl_xor(acc.w, m);
  }
  if (lane < 4) {
    float rd = 1.0f / fmaxf((float)(end - start), 1.0f);
    ushort4 qy = ((const ushort4*)y1h16)[n * 4 + f4];
    float ox = fmaxf(__half2float(__ushort_as_half(qy.x)) + acc.x * rd, 0.f);
    float oy = fmaxf(__half2float(__ushort_as_half(qy.y)) + acc.y * rd, 0.f);
    float oz = fmaxf(__half2float(__ushort_as_half(qy.z)) + acc.z * rd, 0.f);
    float ow = fmaxf(__half2float(__ushort_as_half(qy.w)) + acc.w * rd, 0.f);
    ushort4 o;
    o.x = __half_as_ushort(__float2half(ox));
    o.y = __half_as_ushort(__float2half(oy));
    o.z = __half_as_ushort(__float2half(oz));
    o.w = __half_as_ushort(__float2half(ow));
    ((ushort4*)h16)[n * 4 + f4] = o;
  }
}

// ------- gather layer 2 + output fusion -------------------------------------
__global__ __launch_bounds__(256) void k_gather2_out(
    const __half* __restrict__ h16, const int* __restrict__ A,
    const int* __restrict__ srclist, const float* __restrict__ wn,
    const float* __restrict__ wsf, const float* __restrict__ b,
    float* __restrict__ out) {
  __shared__ float wn_s[H * C];
  __shared__ float ws_s[H * C];
  __shared__ float b_s[C];
  __shared__ alignas(16) float hv_s[4][H];
  __shared__ alignas(16) float mv_s[4][H];
  const int tid = threadIdx.x;
  for (int i = tid; i < H * C; i += 256) {
    wn_s[i] = wn[i];
    ws_s[i] = wsf[i];
  }
  if (tid < C) b_s[tid] = b[tid];

  const int wave = tid >> 6, lane = tid & 63;
  const int n = blockIdx.x * 4 + wave;
  const bool valid = (n < N_NODES);
  int start = 0, end = 0;
  if (valid) {
    end = A[n];
    start = n ? A[n - 1] : 0;
  }
  const int f4 = lane & 3, slot = lane >> 2;
  float4 acc = make_float4(0.f, 0.f, 0.f, 0.f);
  const ushort4* hr = (const ushort4*)h16;
  for (int e = start + slot; e < end; e += 16) {
    int s = srclist[e];
    ushort4 q = hr[s * 4 + f4];
    acc.x += __half2float(__ushort_as_half(q.x));
    acc.y += __half2float(__ushort_as_half(q.y));
    acc.z += __half2float(__ushort_as_half(q.z));
    acc.w += __half2float(__ushort_as_half(q.w));
  }
#pragma unroll
  for (int m = 4; m <= 32; m <<= 1) {
    acc.x += __shfl_xor(acc.x, m);
    acc.y += __shfl_xor(acc.y, m);
    acc.z += __shfl_xor(acc.z, m);
    acc.w += __shfl_xor(acc.w, m);
  }
  __syncthreads();  // weights staged; all waves reach this
  if (valid && lane < 4) {
    float rd = 1.0f / fmaxf((float)(end - start), 1.0f);
    ushort4 qh = hr[n * 4 + f4];
    float* hv = &hv_s[wave][f4 * 4];
    hv[0] = __half2float(__ushort_as_half(qh.x));
    hv[1] = __half2float(__ushort_as_half(qh.y));
    hv[2] = __half2float(__ushort_as_half(qh.z));
    hv[3] = __half2float(__ushort_as_half(qh.w));
    float* mv = &mv_s[wave][f4 * 4];
    mv[0] = acc.x * rd; mv[1] = acc.y * rd;
    mv[2] = acc.z * rd; mv[3] = acc.w * rd;
  }
  __syncthreads();
  if (valid && lane < C) {
    float o = b_s[lane];
#pragma unroll
    for (int jj = 0; jj < H; ++jj)
      o += hv_s[wave][jj] * ws_s[jj * C + lane] +
           mv_s[wave][jj] * wn_s[jj * C + lane];
    out[n * C + lane] = o;
  }
}

extern "C" void kernel_launch(void* const* d_in, const int* in_sizes, int n_in,
                              void* d_out, int out_size, void* d_ws,
                              size_t ws_size, hipStream_t stream) {
  const float* x = (const float*)d_in[0];
  const int* src = (const int*)d_in[1];
  const int* dst = (const int*)d_in[2];
  const float* wn1 = (const float*)d_in[3];
  const float* ws1 = (const float*)d_in[4];
  const float* b1 = (const float*)d_in[5];
  const float* wn2 = (const float*)d_in[6];
  const float* ws2 = (const float*)d_in[7];
  const float* b2 = (const float*)d_in[8];
  float* out = (float*)d_out;

  // xn1 (fp16, 3.2MB) lives in d_out (consumed by k_gather1 before
  // k_gather2_out writes d_out).
  __half* xn1h = (__half*)out;

  // ws layout, 13.2 MB total (identical byte footprint to prior rounds):
  //   [0, 100000)              A: CSR end offsets (int)
  //   [100000, 100391)         counts (int)
  //   [100391, 100782)         starts (int)
  //   [100782, 101173)         cursors (int)
  //   [102400, 102400+E)       P: packed pairs -> srclist in place (int)
  //   [102400+E, +NH/2)        y1 (fp16, NH halves)
  //   [102400+E+NH/2, +NH/2)   h  (fp16, NH halves)
  float* wsp = (float*)d_ws;
  int* A = (int*)wsp;
  int* counts = (int*)wsp + 100000;
  int* starts = (int*)wsp + 100391;
  int* cursors = (int*)wsp + 100782;
  int* P = (int*)(wsp + 102400);
  __half* y1h16 = (__half*)(wsp + 102400 + N_EDGES);
  __half* h16 = (__half*)(wsp + 102400 + N_EDGES + NH / 2);

  k_zero_i<<<2, 256, 0, stream>>>(counts, NBKT);
  k_bcount<<<ABLK, 256, 0, stream>>>(dst, counts);
  k_bscan<<<1, 512, 0, stream>>>(counts, starts, cursors);
  k_bfill<<<ABLK, 256, 0, stream>>>(src, dst, cursors, P);
  k_bcsr<<<NBKT, 256, 0, stream>>>(counts, starts, P, A);
  k_proj1<<<(N_NODES + 63) / 64, 256, 0, stream>>>(x, wn1, ws1, b1, xn1h,
                                                   y1h16);
  k_gather1<<<(N_NODES + 3) / 4, 256, 0, stream>>>(xn1h, A, P, y1h16, h16);
  k_gather2_out<<<(N_NODES + 3) / 4, 256, 0, stream>>>(h16, A, P, wn2, ws2, b2,
                                                       out);
}

// Round 7
// 228.742 us; speedup vs baseline: 1.8922x; 1.0803x over previous
//
#include <hip/hip_runtime.h>
#include <hip/hip_fp16.h>

#define N_NODES 100000
#define N_EDGES 1600000
#define F 128
#define H 16
#define C 40
#define NH (N_NODES * H)
#define NBKT 391   // buckets of 256 nodes: ceil(100000/256)
#define ABLK 256   // partition blocks
#define EPB 6250   // edges per partition block (256*6250 = 1.6M exact)
#define CAP 6144   // per-bucket LDS capacity (mean 4096, ~32 sigma headroom)

__device__ __forceinline__ float cvh(ushort u) {
  return __half2float(__ushort_as_half(u));
}
__device__ __forceinline__ ushort pkh(float f) {
  return __half_as_ushort(__float2half(f));
}

// ---------------- zero-fill (ws is poisoned 0xAA before every launch) -------
__global__ __launch_bounds__(256) void k_zero_i(int* __restrict__ p, int n) {
  int t = blockIdx.x * 256 + threadIdx.x;
  if (t < n) p[t] = 0;
}

// ---------------- bucket counts: LDS hist -> <=391 global atomics/block -----
__global__ __launch_bounds__(256) void k_bcount(const int* __restrict__ dst,
                                                int* __restrict__ counts) {
  __shared__ int cnt[NBKT];
  for (int i = threadIdx.x; i < NBKT; i += 256) cnt[i] = 0;
  __syncthreads();
  const int e0 = blockIdx.x * EPB;
  for (int e = e0 + threadIdx.x; e < e0 + EPB; e += 256)
    atomicAdd(&cnt[dst[e] >> 8], 1);
  __syncthreads();
  for (int i = threadIdx.x; i < NBKT; i += 256)
    if (cnt[i]) atomicAdd(&counts[i], cnt[i]);
}

// ---------------- scan 391 bucket counts -> starts (excl) + cursors copy ----
__global__ __launch_bounds__(512) void k_bscan(const int* __restrict__ counts,
                                               int* __restrict__ starts,
                                               int* __restrict__ cursors) {
  __shared__ int ls[512];
  int tid = threadIdx.x;
  int v = (tid < NBKT) ? counts[tid] : 0;
  ls[tid] = v;
  __syncthreads();
  for (int off = 1; off < 512; off <<= 1) {
    int a = (tid >= off) ? ls[tid - off] : 0;
    __syncthreads();
    ls[tid] += a;
    __syncthreads();
  }
  if (tid < NBKT) {
    int ex = ls[tid] - v;
    starts[tid] = ex;
    cursors[tid] = ex;
  }
}

// ---------------- bucket fill: packed pairs, contiguous per block-bucket ----
// pair = (dlocal<<17) | src  (dlocal<256 -> 8 bits; src<100000 -> 17 bits)
__global__ __launch_bounds__(256) void k_bfill(const int* __restrict__ src,
                                               const int* __restrict__ dst,
                                               int* __restrict__ cursors,
                                               int* __restrict__ P) {
  __shared__ int cnt[NBKT];
  __shared__ int base[NBKT];
  __shared__ int cur[NBKT];
  for (int i = threadIdx.x; i < NBKT; i += 256) {
    cnt[i] = 0;
    cur[i] = 0;
  }
  __syncthreads();
  const int e0 = blockIdx.x * EPB;
  for (int e = e0 + threadIdx.x; e < e0 + EPB; e += 256)
    atomicAdd(&cnt[dst[e] >> 8], 1);
  __syncthreads();
  for (int i = threadIdx.x; i < NBKT; i += 256)
    if (cnt[i]) base[i] = atomicAdd(&cursors[i], cnt[i]);
  __syncthreads();
  for (int e = e0 + threadIdx.x; e < e0 + EPB; e += 256) {
    int d = dst[e], s = src[e];
    int b = d >> 8;
    int off = atomicAdd(&cur[b], 1);
    P[base[b] + off] = ((d & 255) << 17) | s;
  }
}

// ---------------- per-bucket CSR: sort pairs by dlocal entirely in LDS ------
__global__ __launch_bounds__(256) void k_bcsr(const int* __restrict__ counts,
                                              const int* __restrict__ starts,
                                              int* __restrict__ P,
                                              int* __restrict__ A) {
  __shared__ int pbuf[CAP];
  __shared__ int sbuf[CAP];
  __shared__ int h[256];
  __shared__ int cur[256];
  const int b = blockIdx.x, tid = threadIdx.x;
  const int st = starts[b];
  int cnt = counts[b];
  if (cnt > CAP) cnt = CAP;  // ~impossible; guards LDS
  for (int i = tid; i < cnt; i += 256) pbuf[i] = P[st + i];
  h[tid] = 0;
  __syncthreads();
  for (int i = tid; i < cnt; i += 256) atomicAdd(&h[pbuf[i] >> 17], 1);
  __syncthreads();
  int v = h[tid];
  for (int off = 1; off < 256; off <<= 1) {
    int a = (tid >= off) ? h[tid - off] : 0;
    __syncthreads();
    h[tid] += a;
    __syncthreads();
  }
  int incl = h[tid];
  cur[tid] = incl - v;  // exclusive
  int node = b * 256 + tid;
  if (node < N_NODES) A[node] = st + incl;
  __syncthreads();
  for (int i = tid; i < cnt; i += 256) {
    int pv = pbuf[i];
    int nl = pv >> 17;
    int p = atomicAdd(&cur[nl], 1);
    sbuf[p] = pv & 0x1FFFF;
  }
  __syncthreads();
  for (int i = tid; i < cnt; i += 256) P[st + i] = sbuf[i];
}

// ---------------- layer-1 projection: xn1 = x@Wn1, y1 = x@Ws1 + b1 (fp16) ---
__global__ __launch_bounds__(256) void k_proj1(
    const float* __restrict__ x, const float* __restrict__ wn,
    const float* __restrict__ wsf, const float* __restrict__ b,
    __half* __restrict__ xn1h, __half* __restrict__ y1h16) {
  __shared__ alignas(16) float xs[64 * 129];
  const int tid = threadIdx.x;
  const int node0 = blockIdx.x * 64;
  for (int i = tid; i < 64 * 32; i += 256) {
    int r = i >> 5, cv = i & 31;
    int n = node0 + r;
    float4 v = make_float4(0.f, 0.f, 0.f, 0.f);
    if (n < N_NODES) v = ((const float4*)x)[(size_t)n * 32 + cv];
    float* dp = &xs[r * 129 + cv * 4];
    dp[0] = v.x; dp[1] = v.y; dp[2] = v.z; dp[3] = v.w;
  }
  __syncthreads();

  const int wave = __builtin_amdgcn_readfirstlane(tid >> 6);
  const int lane = tid & 63;
  const int n = node0 + lane;
  const float* wmat = (wave < 2) ? wn : wsf;
  const int c0 = (wave & 1) * 8;

  float acc[8] = {0.f, 0.f, 0.f, 0.f, 0.f, 0.f, 0.f, 0.f};
  const float* xrow = &xs[lane * 129];
#pragma unroll 8
  for (int k = 0; k < F; ++k) {
    float xv = xrow[k];
    const float* wr = wmat + k * H + c0;
#pragma unroll
    for (int j = 0; j < 8; ++j) acc[j] += xv * wr[j];
  }
  if (n < N_NODES) {
    union { ushort u[8]; uint4 v; } pk;
    if (wave < 2) {
#pragma unroll
      for (int j = 0; j < 8; ++j) pk.u[j] = pkh(acc[j]);
      *(uint4*)&xn1h[n * H + c0] = pk.v;   // byte 32n+2c0, 16B aligned
    } else {
#pragma unroll
      for (int j = 0; j < 8; ++j) pk.u[j] = pkh(acc[j] + b[c0 + j]);
      *(uint4*)&y1h16[n * H + c0] = pk.v;
    }
  }
}

// ------- gather layer 1 + hidden fusion: h16 = relu(y1 + mean) --------------
// Thread = (node, feature-quad): 16 nodes per wave, 64 per block. Register
// accumulation with explicit ILP-4; no shuffles, no reduce, no staging.
__global__ __launch_bounds__(256) void k_gather1(
    const __half* __restrict__ xn1h, const int* __restrict__ A,
    const int* __restrict__ srclist, const __half* __restrict__ y1h16,
    __half* __restrict__ h16) {
  const int n = blockIdx.x * 64 + (threadIdx.x >> 2);
  const int g = threadIdx.x & 3;
  if (n >= N_NODES) return;  // no __syncthreads in this kernel
  const int end = A[n];
  const int start = n ? A[n - 1] : 0;
  const ushort4* xr = (const ushort4*)xn1h;  // 8B = 4 halves
  float ax = 0.f, ay = 0.f, az = 0.f, aw = 0.f;
  int e = start;
  for (; e + 4 <= end; e += 4) {
    int s0 = srclist[e], s1 = srclist[e + 1];
    int s2 = srclist[e + 2], s3 = srclist[e + 3];
    ushort4 q0 = xr[s0 * 4 + g], q1 = xr[s1 * 4 + g];
    ushort4 q2 = xr[s2 * 4 + g], q3 = xr[s3 * 4 + g];
    ax += cvh(q0.x) + cvh(q1.x) + cvh(q2.x) + cvh(q3.x);
    ay += cvh(q0.y) + cvh(q1.y) + cvh(q2.y) + cvh(q3.y);
    az += cvh(q0.z) + cvh(q1.z) + cvh(q2.z) + cvh(q3.z);
    aw += cvh(q0.w) + cvh(q1.w) + cvh(q2.w) + cvh(q3.w);
  }
  for (; e < end; ++e) {
    ushort4 q = xr[srclist[e] * 4 + g];
    ax += cvh(q.x); ay += cvh(q.y); az += cvh(q.z); aw += cvh(q.w);
  }
  const float rd = 1.0f / fmaxf((float)(end - start), 1.0f);
  ushort4 qy = ((const ushort4*)y1h16)[n * 4 + g];
  ushort4 o;
  o.x = pkh(fmaxf(cvh(qy.x) + ax * rd, 0.f));
  o.y = pkh(fmaxf(cvh(qy.y) + ay * rd, 0.f));
  o.z = pkh(fmaxf(cvh(qy.z) + az * rd, 0.f));
  o.w = pkh(fmaxf(cvh(qy.w) + aw * rd, 0.f));
  ((ushort4*)h16)[n * 4 + g] = o;
}

// ------- gather layer 2 fused with output GEMM ------------------------------
// Phase 1: thread=(node,quad) gathers mean + stages h for 64 nodes into LDS
// (f32, no extra quantization). Phase 2: lane=node, wave=10 output cols,
// weights via wave-uniform scalar loads (proj1 pattern).
__global__ __launch_bounds__(256) void k_gout(
    const __half* __restrict__ h16, const int* __restrict__ A,
    const int* __restrict__ srclist, const float* __restrict__ wn,
    const float* __restrict__ wsf, const float* __restrict__ b,
    float* __restrict__ out) {
  __shared__ float hm[64][33];  // [node][0:16)=h, [16:32)=mean; pad->no conflict
  const int tid = threadIdx.x;
  const int node0 = blockIdx.x * 64;
  const int nl = tid >> 2, g = tid & 3;
  const int n = node0 + nl;
  const ushort4* hr = (const ushort4*)h16;
  if (n < N_NODES) {
    const int end = A[n];
    const int start = n ? A[n - 1] : 0;
    float ax = 0.f, ay = 0.f, az = 0.f, aw = 0.f;
    int e = start;
    for (; e + 4 <= end; e += 4) {
      int s0 = srclist[e], s1 = srclist[e + 1];
      int s2 = srclist[e + 2], s3 = srclist[e + 3];
      ushort4 q0 = hr[s0 * 4 + g], q1 = hr[s1 * 4 + g];
      ushort4 q2 = hr[s2 * 4 + g], q3 = hr[s3 * 4 + g];
      ax += cvh(q0.x) + cvh(q1.x) + cvh(q2.x) + cvh(q3.x);
      ay += cvh(q0.y) + cvh(q1.y) + cvh(q2.y) + cvh(q3.y);
      az += cvh(q0.z) + cvh(q1.z) + cvh(q2.z) + cvh(q3.z);
      aw += cvh(q0.w) + cvh(q1.w) + cvh(q2.w) + cvh(q3.w);
    }
    for (; e < end; ++e) {
      ushort4 q = hr[srclist[e] * 4 + g];
      ax += cvh(q.x); ay += cvh(q.y); az += cvh(q.z); aw += cvh(q.w);
    }
    const float rd = 1.0f / fmaxf((float)(end - start), 1.0f);
    ushort4 qh = hr[n * 4 + g];
    float* hv = &hm[nl][g * 4];
    hv[0] = cvh(qh.x); hv[1] = cvh(qh.y);
    hv[2] = cvh(qh.z); hv[3] = cvh(qh.w);
    float* mv = &hm[nl][16 + g * 4];
    mv[0] = ax * rd; mv[1] = ay * rd; mv[2] = az * rd; mv[3] = aw * rd;
  }
  __syncthreads();

  const int wv = tid >> 6;    // 0..3 -> output col group
  const int lane = tid & 63;  // local node
  const int on = node0 + lane;
  const int c0 = wv * 10;
  float acc[10];
#pragma unroll
  for (int j = 0; j < 10; ++j) acc[j] = b[c0 + j];
#pragma unroll
  for (int k = 0; k < H; ++k) {
    float hv = hm[lane][k];
    const float* wr = wsf + k * C + c0;  // wave-uniform -> s_load
#pragma unroll
    for (int j = 0; j < 10; ++j) acc[j] += hv * wr[j];
  }
#pragma unroll
  for (int k = 0; k < H; ++k) {
    float mv = hm[lane][16 + k];
    const float* wr = wn + k * C + c0;  // wave-uniform -> s_load
#pragma unroll
    for (int j = 0; j < 10; ++j) acc[j] += mv * wr[j];
  }
  if (on < N_NODES) {
#pragma unroll
    for (int j = 0; j < 10; ++j) out[on * C + c0 + j] = acc[j];
  }
}

extern "C" void kernel_launch(void* const* d_in, const int* in_sizes, int n_in,
                              void* d_out, int out_size, void* d_ws,
                              size_t ws_size, hipStream_t stream) {
  const float* x = (const float*)d_in[0];
  const int* src = (const int*)d_in[1];
  const int* dst = (const int*)d_in[2];
  const float* wn1 = (const float*)d_in[3];
  const float* ws1 = (const float*)d_in[4];
  const float* b1 = (const float*)d_in[5];
  const float* wn2 = (const float*)d_in[6];
  const float* ws2 = (const float*)d_in[7];
  const float* b2 = (const float*)d_in[8];
  float* out = (float*)d_out;

  // xn1 (fp16, 3.2MB) lives in d_out (consumed by k_gather1 before
  // k_gout writes d_out).
  __half* xn1h = (__half*)out;

  // ws layout, 13.2 MB total (identical byte footprint to prior rounds):
  //   [0, 100000)              A: CSR end offsets (int)
  //   [100000, 100391)         counts (int)
  //   [100391, 100782)         starts (int)
  //   [100782, 101173)         cursors (int)
  //   [102400, 102400+E)       P: packed pairs -> srclist in place (int)
  //   [102400+E, +NH/2)        y1 (fp16, NH halves)
  //   [102400+E+NH/2, +NH/2)   h  (fp16, NH halves)
  float* wsp = (float*)d_ws;
  int* A = (int*)wsp;
  int* counts = (int*)wsp + 100000;
  int* starts = (int*)wsp + 100391;
  int* cursors = (int*)wsp + 100782;
  int* P = (int*)(wsp + 102400);
  __half* y1h16 = (__half*)(wsp + 102400 + N_EDGES);
  __half* h16 = (__half*)(wsp + 102400 + N_EDGES + NH / 2);

  k_zero_i<<<2, 256, 0, stream>>>(counts, NBKT);
  k_bcount<<<ABLK, 256, 0, stream>>>(dst, counts);
  k_bscan<<<1, 512, 0, stream>>>(counts, starts, cursors);
  k_bfill<<<ABLK, 256, 0, stream>>>(src, dst, cursors, P);
  k_bcsr<<<NBKT, 256, 0, stream>>>(counts, starts, P, A);
  k_proj1<<<(N_NODES + 63) / 64, 256, 0, stream>>>(x, wn1, ws1, b1, xn1h,
                                                   y1h16);
  k_gather1<<<(N_NODES + 63) / 64, 256, 0, stream>>>(xn1h, A, P, y1h16, h16);
  k_gout<<<(N_NODES + 63) / 64, 256, 0, stream>>>(h16, A, P, wn2, ws2, b2,
                                                  out);
}

// Round 8
// 225.631 us; speedup vs baseline: 1.9183x; 1.0138x over previous
//
#include <hip/hip_runtime.h>
#include <hip/hip_fp16.h>

#define N_NODES 100000
#define N_EDGES 1600000
#define F 128
#define H 16
#define C 40
#define NH (N_NODES * H)
#define NBKT 391   // buckets of 256 nodes: ceil(100000/256)
#define ABLK 256   // partition blocks
#define EPB 6250   // edges per partition block (256*6250 = 1.6M exact)
#define CAP 6144   // per-bucket LDS capacity (mean 4096, ~32 sigma headroom)

__device__ __forceinline__ float cvh(ushort u) {
  return __half2float(__ushort_as_half(u));
}
__device__ __forceinline__ ushort pkh(float f) {
  return __half_as_ushort(__float2half(f));
}

// ---------------- zero-fill (ws is poisoned 0xAA before every launch) -------
__global__ __launch_bounds__(256) void k_zero_i(int* __restrict__ p, int n) {
  int t = blockIdx.x * 256 + threadIdx.x;
  if (t < n) p[t] = 0;
}

// ---------------- bucket counts: LDS hist -> <=391 global atomics/block -----
__global__ __launch_bounds__(256) void k_bcount(const int* __restrict__ dst,
                                                int* __restrict__ counts) {
  __shared__ int cnt[NBKT];
  for (int i = threadIdx.x; i < NBKT; i += 256) cnt[i] = 0;
  __syncthreads();
  const int e0 = blockIdx.x * EPB;
  for (int e = e0 + threadIdx.x; e < e0 + EPB; e += 256)
    atomicAdd(&cnt[dst[e] >> 8], 1);
  __syncthreads();
  for (int i = threadIdx.x; i < NBKT; i += 256)
    if (cnt[i]) atomicAdd(&counts[i], cnt[i]);
}

// ---------------- scan 391 bucket counts -> starts (excl) + cursors copy ----
__global__ __launch_bounds__(512) void k_bscan(const int* __restrict__ counts,
                                               int* __restrict__ starts,
                                               int* __restrict__ cursors) {
  __shared__ int ls[512];
  int tid = threadIdx.x;
  int v = (tid < NBKT) ? counts[tid] : 0;
  ls[tid] = v;
  __syncthreads();
  for (int off = 1; off < 512; off <<= 1) {
    int a = (tid >= off) ? ls[tid - off] : 0;
    __syncthreads();
    ls[tid] += a;
    __syncthreads();
  }
  if (tid < NBKT) {
    int ex = ls[tid] - v;
    starts[tid] = ex;
    cursors[tid] = ex;
  }
}

// ---------------- bucket fill: packed pairs, contiguous per block-bucket ----
// pair = (dlocal<<17) | src  (dlocal<256 -> 8 bits; src<100000 -> 17 bits)
__global__ __launch_bounds__(256) void k_bfill(const int* __restrict__ src,
                                               const int* __restrict__ dst,
                                               int* __restrict__ cursors,
                                               int* __restrict__ P) {
  __shared__ int cnt[NBKT];
  __shared__ int base[NBKT];
  __shared__ int cur[NBKT];
  for (int i = threadIdx.x; i < NBKT; i += 256) {
    cnt[i] = 0;
    cur[i] = 0;
  }
  __syncthreads();
  const int e0 = blockIdx.x * EPB;
  for (int e = e0 + threadIdx.x; e < e0 + EPB; e += 256)
    atomicAdd(&cnt[dst[e] >> 8], 1);
  __syncthreads();
  for (int i = threadIdx.x; i < NBKT; i += 256)
    if (cnt[i]) base[i] = atomicAdd(&cursors[i], cnt[i]);
  __syncthreads();
  for (int e = e0 + threadIdx.x; e < e0 + EPB; e += 256) {
    int d = dst[e], s = src[e];
    int b = d >> 8;
    int off = atomicAdd(&cur[b], 1);
    P[base[b] + off] = ((d & 255) << 17) | s;
  }
}

// ---------------- per-bucket CSR: sort pairs by dlocal entirely in LDS ------
__global__ __launch_bounds__(256) void k_bcsr(const int* __restrict__ counts,
                                              const int* __restrict__ starts,
                                              int* __restrict__ P,
                                              int* __restrict__ A) {
  __shared__ int pbuf[CAP];
  __shared__ int sbuf[CAP];
  __shared__ int h[256];
  __shared__ int cur[256];
  const int b = blockIdx.x, tid = threadIdx.x;
  const int st = starts[b];
  int cnt = counts[b];
  if (cnt > CAP) cnt = CAP;  // ~impossible; guards LDS
  for (int i = tid; i < cnt; i += 256) pbuf[i] = P[st + i];
  h[tid] = 0;
  __syncthreads();
  for (int i = tid; i < cnt; i += 256) atomicAdd(&h[pbuf[i] >> 17], 1);
  __syncthreads();
  int v = h[tid];
  for (int off = 1; off < 256; off <<= 1) {
    int a = (tid >= off) ? h[tid - off] : 0;
    __syncthreads();
    h[tid] += a;
    __syncthreads();
  }
  int incl = h[tid];
  cur[tid] = incl - v;  // exclusive
  int node = b * 256 + tid;
  if (node < N_NODES) A[node] = st + incl;
  __syncthreads();
  for (int i = tid; i < cnt; i += 256) {
    int pv = pbuf[i];
    int nl = pv >> 17;
    int p = atomicAdd(&cur[nl], 1);
    sbuf[p] = pv & 0x1FFFF;
  }
  __syncthreads();
  for (int i = tid; i < cnt; i += 256) P[st + i] = sbuf[i];
}

// ---------------- layer-1 projection: xn1 = x@Wn1, y1 = x@Ws1 + b1 (fp16) ---
__global__ __launch_bounds__(256) void k_proj1(
    const float* __restrict__ x, const float* __restrict__ wn,
    const float* __restrict__ wsf, const float* __restrict__ b,
    __half* __restrict__ xn1h, __half* __restrict__ y1h16) {
  __shared__ alignas(16) float xs[64 * 129];
  const int tid = threadIdx.x;
  const int node0 = blockIdx.x * 64;
  for (int i = tid; i < 64 * 32; i += 256) {
    int r = i >> 5, cv = i & 31;
    int n = node0 + r;
    float4 v = make_float4(0.f, 0.f, 0.f, 0.f);
    if (n < N_NODES) v = ((const float4*)x)[(size_t)n * 32 + cv];
    float* dp = &xs[r * 129 + cv * 4];
    dp[0] = v.x; dp[1] = v.y; dp[2] = v.z; dp[3] = v.w;
  }
  __syncthreads();

  const int wave = __builtin_amdgcn_readfirstlane(tid >> 6);
  const int lane = tid & 63;
  const int n = node0 + lane;
  const float* wmat = (wave < 2) ? wn : wsf;
  const int c0 = (wave & 1) * 8;

  float acc[8] = {0.f, 0.f, 0.f, 0.f, 0.f, 0.f, 0.f, 0.f};
  const float* xrow = &xs[lane * 129];
#pragma unroll 8
  for (int k = 0; k < F; ++k) {
    float xv = xrow[k];
    const float* wr = wmat + k * H + c0;
#pragma unroll
    for (int j = 0; j < 8; ++j) acc[j] += xv * wr[j];
  }
  if (n < N_NODES) {
    union { ushort u[8]; uint4 v; } pk;
    if (wave < 2) {
#pragma unroll
      for (int j = 0; j < 8; ++j) pk.u[j] = pkh(acc[j]);
      *(uint4*)&xn1h[n * H + c0] = pk.v;   // byte 32n+2c0, 16B aligned
    } else {
#pragma unroll
      for (int j = 0; j < 8; ++j) pk.u[j] = pkh(acc[j] + b[c0 + j]);
      *(uint4*)&y1h16[n * H + c0] = pk.v;
    }
  }
}

// ---- edge-sum macro body: accumulate quad g of rows in [start+s, end) step 2
// with ILP-8 / ILP-4 / tail; rows from fp16 table tab (ushort4-indexed).
#define GATHER_QUAD(tab)                                                    \
  {                                                                         \
    int e = start + s;                                                      \
    for (; e + 14 < end; e += 16) {                                         \
      int i0 = srclist[e], i1 = srclist[e + 2], i2 = srclist[e + 4],        \
          i3 = srclist[e + 6], i4 = srclist[e + 8], i5 = srclist[e + 10],   \
          i6 = srclist[e + 12], i7 = srclist[e + 14];                       \
      ushort4 q0 = tab[i0 * 4 + g], q1 = tab[i1 * 4 + g];                   \
      ushort4 q2 = tab[i2 * 4 + g], q3 = tab[i3 * 4 + g];                   \
      ushort4 q4 = tab[i4 * 4 + g], q5 = tab[i5 * 4 + g];                   \
      ushort4 q6 = tab[i6 * 4 + g], q7 = tab[i7 * 4 + g];                   \
      ax += cvh(q0.x) + cvh(q1.x) + cvh(q2.x) + cvh(q3.x) + cvh(q4.x) +     \
            cvh(q5.x) + cvh(q6.x) + cvh(q7.x);                              \
      ay += cvh(q0.y) + cvh(q1.y) + cvh(q2.y) + cvh(q3.y) + cvh(q4.y) +     \
            cvh(q5.y) + cvh(q6.y) + cvh(q7.y);                              \
      az += cvh(q0.z) + cvh(q1.z) + cvh(q2.z) + cvh(q3.z) + cvh(q4.z) +     \
            cvh(q5.z) + cvh(q6.z) + cvh(q7.z);                              \
      aw += cvh(q0.w) + cvh(q1.w) + cvh(q2.w) + cvh(q3.w) + cvh(q4.w) +     \
            cvh(q5.w) + cvh(q6.w) + cvh(q7.w);                              \
    }                                                                       \
    for (; e + 6 < end; e += 8) {                                           \
      int i0 = srclist[e], i1 = srclist[e + 2], i2 = srclist[e + 4],        \
          i3 = srclist[e + 6];                                              \
      ushort4 q0 = tab[i0 * 4 + g], q1 = tab[i1 * 4 + g];                   \
      ushort4 q2 = tab[i2 * 4 + g], q3 = tab[i3 * 4 + g];                   \
      ax += cvh(q0.x) + cvh(q1.x) + cvh(q2.x) + cvh(q3.x);                  \
      ay += cvh(q0.y) + cvh(q1.y) + cvh(q2.y) + cvh(q3.y);                  \
      az += cvh(q0.z) + cvh(q1.z) + cvh(q2.z) + cvh(q3.z);                  \
      aw += cvh(q0.w) + cvh(q1.w) + cvh(q2.w) + cvh(q3.w);                  \
    }                                                                       \
    for (; e < end; e += 2) {                                               \
      ushort4 q = tab[srclist[e] * 4 + g];                                  \
      ax += cvh(q.x); ay += cvh(q.y); az += cvh(q.z); aw += cvh(q.w);       \
    }                                                                       \
  }

// ------- gather layer 1 + hidden fusion: h16 = relu(y1 + mean) --------------
// 8 threads/node = 4 quads x 2 edge slots; 64 nodes per 512-thread block.
// ILP-8 batches -> ~2 dependent load rounds/thread; 4 shfl_xor to merge slots.
__global__ __launch_bounds__(512) void k_gather1(
    const __half* __restrict__ xn1h, const int* __restrict__ A,
    const int* __restrict__ srclist, const __half* __restrict__ y1h16,
    __half* __restrict__ h16) {
  const int tid = threadIdx.x;
  const int n = blockIdx.x * 64 + (tid >> 3);
  const int g = tid & 3;          // feature quad
  const int s = (tid >> 2) & 1;   // edge slot
  if (n >= N_NODES) return;  // no __syncthreads in this kernel
  const int end = A[n];
  const int start = n ? A[n - 1] : 0;
  const ushort4* xr = (const ushort4*)xn1h;
  float ax = 0.f, ay = 0.f, az = 0.f, aw = 0.f;
  GATHER_QUAD(xr)
  ax += __shfl_xor(ax, 4);
  ay += __shfl_xor(ay, 4);
  az += __shfl_xor(az, 4);
  aw += __shfl_xor(aw, 4);
  if (s == 0) {
    const float rd = 1.0f / fmaxf((float)(end - start), 1.0f);
    ushort4 qy = ((const ushort4*)y1h16)[n * 4 + g];
    ushort4 o;
    o.x = pkh(fmaxf(cvh(qy.x) + ax * rd, 0.f));
    o.y = pkh(fmaxf(cvh(qy.y) + ay * rd, 0.f));
    o.z = pkh(fmaxf(cvh(qy.z) + az * rd, 0.f));
    o.w = pkh(fmaxf(cvh(qy.w) + aw * rd, 0.f));
    ((ushort4*)h16)[n * 4 + g] = o;
  }
}

// ------- gather layer 2 fused with output GEMM ------------------------------
// Phase 1: 8 threads/node gather mean + stage h for 64 nodes into LDS (f32).
// Phase 2: all 8 waves; lane=node, wave=5 output cols, wave-uniform weights.
__global__ __launch_bounds__(512) void k_gout(
    const __half* __restrict__ h16, const int* __restrict__ A,
    const int* __restrict__ srclist, const float* __restrict__ wn,
    const float* __restrict__ wsf, const float* __restrict__ b,
    float* __restrict__ out) {
  __shared__ float hm[64][33];  // [node][0:16)=h, [16:32)=mean; pad 33
  const int tid = threadIdx.x;
  const int node0 = blockIdx.x * 64;
  const int nl = tid >> 3, g = tid & 3, s = (tid >> 2) & 1;
  const int n = node0 + nl;
  const ushort4* hr = (const ushort4*)h16;
  if (n < N_NODES) {
    const int end = A[n];
    const int start = n ? A[n - 1] : 0;
    float ax = 0.f, ay = 0.f, az = 0.f, aw = 0.f;
    GATHER_QUAD(hr)
    ax += __shfl_xor(ax, 4);
    ay += __shfl_xor(ay, 4);
    az += __shfl_xor(az, 4);
    aw += __shfl_xor(aw, 4);
    if (s == 0) {
      const float rd = 1.0f / fmaxf((float)(end - start), 1.0f);
      ushort4 qh = hr[n * 4 + g];
      float* hv = &hm[nl][g * 4];
      hv[0] = cvh(qh.x); hv[1] = cvh(qh.y);
      hv[2] = cvh(qh.z); hv[3] = cvh(qh.w);
      float* mv = &hm[nl][16 + g * 4];
      mv[0] = ax * rd; mv[1] = ay * rd; mv[2] = az * rd; mv[3] = aw * rd;
    }
  }
  __syncthreads();

  const int wv = tid >> 6;    // 0..7 -> 5-col group
  const int lane = tid & 63;  // local node
  const int on = node0 + lane;
  const int c0 = wv * 5;
  float acc[5];
#pragma unroll
  for (int j = 0; j < 5; ++j) acc[j] = b[c0 + j];
#pragma unroll
  for (int k = 0; k < H; ++k) {
    float hv = hm[lane][k];
    const float* wr = wsf + k * C + c0;  // wave-uniform -> s_load
#pragma unroll
    for (int j = 0; j < 5; ++j) acc[j] += hv * wr[j];
  }
#pragma unroll
  for (int k = 0; k < H; ++k) {
    float mv = hm[lane][16 + k];
    const float* wr = wn + k * C + c0;  // wave-uniform -> s_load
#pragma unroll
    for (int j = 0; j < 5; ++j) acc[j] += mv * wr[j];
  }
  if (on < N_NODES) {
#pragma unroll
    for (int j = 0; j < 5; ++j) out[on * C + c0 + j] = acc[j];
  }
}

extern "C" void kernel_launch(void* const* d_in, const int* in_sizes, int n_in,
                              void* d_out, int out_size, void* d_ws,
                              size_t ws_size, hipStream_t stream) {
  const float* x = (const float*)d_in[0];
  const int* src = (const int*)d_in[1];
  const int* dst = (const int*)d_in[2];
  const float* wn1 = (const float*)d_in[3];
  const float* ws1 = (const float*)d_in[4];
  const float* b1 = (const float*)d_in[5];
  const float* wn2 = (const float*)d_in[6];
  const float* ws2 = (const float*)d_in[7];
  const float* b2 = (const float*)d_in[8];
  float* out = (float*)d_out;

  // xn1 (fp16, 3.2MB) lives in d_out (consumed by k_gather1 before
  // k_gout writes d_out).
  __half* xn1h = (__half*)out;

  // ws layout, 13.2 MB total (identical byte footprint to prior rounds):
  //   [0, 100000)              A: CSR end offsets (int)
  //   [100000, 100391)         counts (int)
  //   [100391, 100782)         starts (int)
  //   [100782, 101173)         cursors (int)
  //   [102400, 102400+E)       P: packed pairs -> srclist in place (int)
  //   [102400+E, +NH/2)        y1 (fp16, NH halves)
  //   [102400+E+NH/2, +NH/2)   h  (fp16, NH halves)
  float* wsp = (float*)d_ws;
  int* A = (int*)wsp;
  int* counts = (int*)wsp + 100000;
  int* starts = (int*)wsp + 100391;
  int* cursors = (int*)wsp + 100782;
  int* P = (int*)(wsp + 102400);
  __half* y1h16 = (__half*)(wsp + 102400 + N_EDGES);
  __half* h16 = (__half*)(wsp + 102400 + N_EDGES + NH / 2);

  k_zero_i<<<2, 256, 0, stream>>>(counts, NBKT);
  k_bcount<<<ABLK, 256, 0, stream>>>(dst, counts);
  k_bscan<<<1, 512, 0, stream>>>(counts, starts, cursors);
  k_bfill<<<ABLK, 256, 0, stream>>>(src, dst, cursors, P);
  k_bcsr<<<NBKT, 256, 0, stream>>>(counts, starts, P, A);
  k_proj1<<<(N_NODES + 63) / 64, 256, 0, stream>>>(x, wn1, ws1, b1, xn1h,
                                                   y1h16);
  k_gather1<<<(N_NODES + 63) / 64, 512, 0, stream>>>(xn1h, A, P, y1h16, h16);
  k_gout<<<(N_NODES + 63) / 64, 512, 0, stream>>>(h16, A, P, wn2, ws2, b2,
                                                  out);
}

// Round 9
// 218.806 us; speedup vs baseline: 1.9781x; 1.0312x over previous
//
#include <hip/hip_runtime.h>
#include <hip/hip_fp16.h>

#define N_NODES 100000
#define N_EDGES 1600000
#define F 128
#define H 16
#define C 40
#define NH (N_NODES * H)
#define NBKT 391   // buckets of 256 nodes: ceil(100000/256)
#define ABLK 256   // partition blocks
#define EPB 6250   // edges per partition block (256*6250 = 1.6M exact)
#define CAP 6144   // per-bucket LDS capacity (mean 4096, ~32 sigma headroom)
#define PROJB 1563 // proj1 blocks: ceil(100000/64)

__device__ __forceinline__ float cvh(ushort u) {
  return __half2float(__ushort_as_half(u));
}
__device__ __forceinline__ ushort pkh(float f) {
  return __half_as_ushort(__float2half(f));
}

// ---------------- CSR build 1: per-block bucket rows (plain stores) ---------
// pc[bid][bucket] = #edges of this block's chunk landing in bucket.
// No global atomics, no pre-zero needed (every cell written).
__global__ __launch_bounds__(256) void k_pcount(const int* __restrict__ dst,
                                                int* __restrict__ pc) {
  __shared__ int cnt[NBKT];
  for (int i = threadIdx.x; i < NBKT; i += 256) cnt[i] = 0;
  __syncthreads();
  const int e0 = blockIdx.x * EPB;
  for (int e = e0 + threadIdx.x; e < e0 + EPB; e += 256)
    atomicAdd(&cnt[dst[e] >> 8], 1);
  __syncthreads();
  for (int i = threadIdx.x; i < NBKT; i += 256)
    pc[blockIdx.x * NBKT + i] = cnt[i];
}

// ---------------- CSR build 2: column scan -> per-block bases in place ------
// One block. For bucket t: total over 256 rows -> block-scan -> global start
// S[t]; rewrite pc[b][t] = S[t] + prefix (exclusive per-block base).
__global__ __launch_bounds__(512) void k_pscan(int* __restrict__ pc,
                                               int* __restrict__ starts,
                                               int* __restrict__ counts) {
  __shared__ int ls[512];
  const int t = threadIdx.x;
  int tot = 0;
  if (t < NBKT)
    for (int b = 0; b < ABLK; ++b) tot += pc[b * NBKT + t];
  ls[t] = tot;
  __syncthreads();
  for (int off = 1; off < 512; off <<= 1) {
    int a = (t >= off) ? ls[t - off] : 0;
    __syncthreads();
    ls[t] += a;
    __syncthreads();
  }
  if (t < NBKT) {
    int S = ls[t] - tot;  // exclusive global start
    starts[t] = S;
    counts[t] = tot;
    int run = S;
    for (int b = 0; b < ABLK; ++b) {
      int v = pc[b * NBKT + t];
      pc[b * NBKT + t] = run;
      run += v;
    }
  }
}

// ---------------- CSR build 3 (blocks 0..255) fused with proj1 (rest) -------
// pfill: one edge pass, LDS cursors only — pos = base[bucket] + cur[bucket]++.
// proj1: xn1 = x@Wn1 (fp16), y1 = x@Ws1 + b1 (fp16). Independent work, merged
// to overlap pfill's latency-bound edge pass with proj1's HBM+VALU work.
// pair = (dlocal<<17) | src  (dlocal<256 -> 8 bits; src<100000 -> 17 bits)
__global__ __launch_bounds__(256) void k_fill_proj(
    const float* __restrict__ x, const float* __restrict__ wn1,
    const float* __restrict__ ws1, const float* __restrict__ b1,
    const int* __restrict__ src, const int* __restrict__ dst,
    const int* __restrict__ pc, int* __restrict__ P,
    __half* __restrict__ xn1h, __half* __restrict__ y1h16) {
  __shared__ alignas(16) float xs[64 * 129];  // 33 KB; pfill aliases into it
  const int tid = threadIdx.x;
  if (blockIdx.x < ABLK) {
    int* base_s = (int*)xs;          // [NBKT]
    int* cur = (int*)xs + NBKT;      // [NBKT]
    for (int i = tid; i < NBKT; i += 256) {
      base_s[i] = pc[blockIdx.x * NBKT + i];
      cur[i] = 0;
    }
    __syncthreads();
    const int e0 = blockIdx.x * EPB;
    for (int e = e0 + tid; e < e0 + EPB; e += 256) {
      int d = dst[e], s = src[e];
      int b = d >> 8;
      int off = atomicAdd(&cur[b], 1);
      P[base_s[b] + off] = ((d & 255) << 17) | s;
    }
    return;
  }
  // ---- proj1 role ----
  const int node0 = (blockIdx.x - ABLK) * 64;
  for (int i = tid; i < 64 * 32; i += 256) {
    int r = i >> 5, cv = i & 31;
    int n = node0 + r;
    float4 v = make_float4(0.f, 0.f, 0.f, 0.f);
    if (n < N_NODES) v = ((const float4*)x)[(size_t)n * 32 + cv];
    float* dp = &xs[r * 129 + cv * 4];
    dp[0] = v.x; dp[1] = v.y; dp[2] = v.z; dp[3] = v.w;
  }
  __syncthreads();

  const int wave = __builtin_amdgcn_readfirstlane(tid >> 6);
  const int lane = tid & 63;
  const int n = node0 + lane;
  const float* wmat = (wave < 2) ? wn1 : ws1;
  const int c0 = (wave & 1) * 8;

  float acc[8] = {0.f, 0.f, 0.f, 0.f, 0.f, 0.f, 0.f, 0.f};
  const float* xrow = &xs[lane * 129];
#pragma unroll 8
  for (int k = 0; k < F; ++k) {
    float xv = xrow[k];
    const float* wr = wmat + k * H + c0;
#pragma unroll
    for (int j = 0; j < 8; ++j) acc[j] += xv * wr[j];
  }
  if (n < N_NODES) {
    union { ushort u[8]; uint4 v; } pk;
    if (wave < 2) {
#pragma unroll
      for (int j = 0; j < 8; ++j) pk.u[j] = pkh(acc[j]);
      *(uint4*)&xn1h[n * H + c0] = pk.v;   // byte 32n+2c0, 16B aligned
    } else {
#pragma unroll
      for (int j = 0; j < 8; ++j) pk.u[j] = pkh(acc[j] + b1[c0 + j]);
      *(uint4*)&y1h16[n * H + c0] = pk.v;
    }
  }
}

// ---------------- per-bucket CSR: sort pairs by dlocal entirely in LDS ------
__global__ __launch_bounds__(256) void k_bcsr(const int* __restrict__ counts,
                                              const int* __restrict__ starts,
                                              int* __restrict__ P,
                                              int* __restrict__ A) {
  __shared__ int pbuf[CAP];
  __shared__ int sbuf[CAP];
  __shared__ int h[256];
  __shared__ int cur[256];
  const int b = blockIdx.x, tid = threadIdx.x;
  const int st = starts[b];
  int cnt = counts[b];
  if (cnt > CAP) cnt = CAP;  // ~impossible; guards LDS
  for (int i = tid; i < cnt; i += 256) pbuf[i] = P[st + i];
  h[tid] = 0;
  __syncthreads();
  for (int i = tid; i < cnt; i += 256) atomicAdd(&h[pbuf[i] >> 17], 1);
  __syncthreads();
  int v = h[tid];
  for (int off = 1; off < 256; off <<= 1) {
    int a = (tid >= off) ? h[tid - off] : 0;
    __syncthreads();
    h[tid] += a;
    __syncthreads();
  }
  int incl = h[tid];
  cur[tid] = incl - v;  // exclusive
  int node = b * 256 + tid;
  if (node < N_NODES) A[node] = st + incl;
  __syncthreads();
  for (int i = tid; i < cnt; i += 256) {
    int pv = pbuf[i];
    int nl = pv >> 17;
    int p = atomicAdd(&cur[nl], 1);
    sbuf[p] = pv & 0x1FFFF;
  }
  __syncthreads();
  for (int i = tid; i < cnt; i += 256) P[st + i] = sbuf[i];
}

// ---- edge-sum macro body: accumulate quad g of rows in [start+s, end) step 2
// with ILP-8 / ILP-4 / tail; rows from fp16 table tab (ushort4-indexed).
#define GATHER_QUAD(tab)                                                    \
  {                                                                         \
    int e = start + s;                                                      \
    for (; e + 14 < end; e += 16) {                                         \
      int i0 = srclist[e], i1 = srclist[e + 2], i2 = srclist[e + 4],        \
          i3 = srclist[e + 6], i4 = srclist[e + 8], i5 = srclist[e + 10],   \
          i6 = srclist[e + 12], i7 = srclist[e + 14];                       \
      ushort4 q0 = tab[i0 * 4 + g], q1 = tab[i1 * 4 + g];                   \
      ushort4 q2 = tab[i2 * 4 + g], q3 = tab[i3 * 4 + g];                   \
      ushort4 q4 = tab[i4 * 4 + g], q5 = tab[i5 * 4 + g];                   \
      ushort4 q6 = tab[i6 * 4 + g], q7 = tab[i7 * 4 + g];                   \
      ax += cvh(q0.x) + cvh(q1.x) + cvh(q2.x) + cvh(q3.x) + cvh(q4.x) +     \
            cvh(q5.x) + cvh(q6.x) + cvh(q7.x);                              \
      ay += cvh(q0.y) + cvh(q1.y) + cvh(q2.y) + cvh(q3.y) + cvh(q4.y) +     \
            cvh(q5.y) + cvh(q6.y) + cvh(q7.y);                              \
      az += cvh(q0.z) + cvh(q1.z) + cvh(q2.z) + cvh(q3.z) + cvh(q4.z) +     \
            cvh(q5.z) + cvh(q6.z) + cvh(q7.z);                              \
      aw += cvh(q0.w) + cvh(q1.w) + cvh(q2.w) + cvh(q3.w) + cvh(q4.w) +     \
            cvh(q5.w) + cvh(q6.w) + cvh(q7.w);                              \
    }                                                                       \
    for (; e + 6 < end; e += 8) {                                           \
      int i0 = srclist[e], i1 = srclist[e + 2], i2 = srclist[e + 4],        \
          i3 = srclist[e + 6];                                              \
      ushort4 q0 = tab[i0 * 4 + g], q1 = tab[i1 * 4 + g];                   \
      ushort4 q2 = tab[i2 * 4 + g], q3 = tab[i3 * 4 + g];                   \
      ax += cvh(q0.x) + cvh(q1.x) + cvh(q2.x) + cvh(q3.x);                  \
      ay += cvh(q0.y) + cvh(q1.y) + cvh(q2.y) + cvh(q3.y);                  \
      az += cvh(q0.z) + cvh(q1.z) + cvh(q2.z) + cvh(q3.z);                  \
      aw += cvh(q0.w) + cvh(q1.w) + cvh(q2.w) + cvh(q3.w);                  \
    }                                                                       \
    for (; e < end; e += 2) {                                               \
      ushort4 q = tab[srclist[e] * 4 + g];                                  \
      ax += cvh(q.x); ay += cvh(q.y); az += cvh(q.z); aw += cvh(q.w);       \
    }                                                                       \
  }

// ------- gather layer 1 + hidden fusion: h16 = relu(y1 + mean) --------------
// 8 threads/node = 4 quads x 2 edge slots; 32 nodes per 256-thread block
// (finer blocks -> finer tail). Barrier-free.
__global__ __launch_bounds__(256) void k_gather1(
    const __half* __restrict__ xn1h, const int* __restrict__ A,
    const int* __restrict__ srclist, const __half* __restrict__ y1h16,
    __half* __restrict__ h16) {
  const int tid = threadIdx.x;
  const int n = blockIdx.x * 32 + (tid >> 3);
  const int g = tid & 3;          // feature quad
  const int s = (tid >> 2) & 1;   // edge slot
  if (n >= N_NODES) return;  // no __syncthreads in this kernel
  const int end = A[n];
  const int start = n ? A[n - 1] : 0;
  const ushort4* xr = (const ushort4*)xn1h;
  float ax = 0.f, ay = 0.f, az = 0.f, aw = 0.f;
  GATHER_QUAD(xr)
  ax += __shfl_xor(ax, 4);
  ay += __shfl_xor(ay, 4);
  az += __shfl_xor(az, 4);
  aw += __shfl_xor(aw, 4);
  if (s == 0) {
    const float rd = 1.0f / fmaxf((float)(end - start), 1.0f);
    ushort4 qy = ((const ushort4*)y1h16)[n * 4 + g];
    ushort4 o;
    o.x = pkh(fmaxf(cvh(qy.x) + ax * rd, 0.f));
    o.y = pkh(fmaxf(cvh(qy.y) + ay * rd, 0.f));
    o.z = pkh(fmaxf(cvh(qy.z) + az * rd, 0.f));
    o.w = pkh(fmaxf(cvh(qy.w) + aw * rd, 0.f));
    ((ushort4*)h16)[n * 4 + g] = o;
  }
}

// ------- gather layer 2 fused with output GEMM ------------------------------
// Phase 1: 8 threads/node gather mean + stage h for 64 nodes into LDS (f32).
// Phase 2: all 8 waves; lane=node, wave=5 output cols, wave-uniform weights.
__global__ __launch_bounds__(512) void k_gout(
    const __half* __restrict__ h16, const int* __restrict__ A,
    const int* __restrict__ srclist, const float* __restrict__ wn,
    const float* __restrict__ wsf, const float* __restrict__ b,
    float* __restrict__ out) {
  __shared__ float hm[64][33];  // [node][0:16)=h, [16:32)=mean; pad 33
  const int tid = threadIdx.x;
  const int node0 = blockIdx.x * 64;
  const int nl = tid >> 3, g = tid & 3, s = (tid >> 2) & 1;
  const int n = node0 + nl;
  const ushort4* hr = (const ushort4*)h16;
  if (n < N_NODES) {
    const int end = A[n];
    const int start = n ? A[n - 1] : 0;
    float ax = 0.f, ay = 0.f, az = 0.f, aw = 0.f;
    GATHER_QUAD(hr)
    ax += __shfl_xor(ax, 4);
    ay += __shfl_xor(ay, 4);
    az += __shfl_xor(az, 4);
    aw += __shfl_xor(aw, 4);
    if (s == 0) {
      const float rd = 1.0f / fmaxf((float)(end - start), 1.0f);
      ushort4 qh = hr[n * 4 + g];
      float* hv = &hm[nl][g * 4];
      hv[0] = cvh(qh.x); hv[1] = cvh(qh.y);
      hv[2] = cvh(qh.z); hv[3] = cvh(qh.w);
      float* mv = &hm[nl][16 + g * 4];
      mv[0] = ax * rd; mv[1] = ay * rd; mv[2] = az * rd; mv[3] = aw * rd;
    }
  }
  __syncthreads();

  const int wv = tid >> 6;    // 0..7 -> 5-col group
  const int lane = tid & 63;  // local node
  const int on = node0 + lane;
  const int c0 = wv * 5;
  float acc[5];
#pragma unroll
  for (int j = 0; j < 5; ++j) acc[j] = b[c0 + j];
#pragma unroll
  for (int k = 0; k < H; ++k) {
    float hv = hm[lane][k];
    const float* wr = wsf + k * C + c0;  // wave-uniform -> s_load
#pragma unroll
    for (int j = 0; j < 5; ++j) acc[j] += hv * wr[j];
  }
#pragma unroll
  for (int k = 0; k < H; ++k) {
    float mv = hm[lane][16 + k];
    const float* wr = wn + k * C + c0;  // wave-uniform -> s_load
#pragma unroll
    for (int j = 0; j < 5; ++j) acc[j] += mv * wr[j];
  }
  if (on < N_NODES) {
#pragma unroll
    for (int j = 0; j < 5; ++j) out[on * C + c0 + j] = acc[j];
  }
}

extern "C" void kernel_launch(void* const* d_in, const int* in_sizes, int n_in,
                              void* d_out, int out_size, void* d_ws,
                              size_t ws_size, hipStream_t stream) {
  const float* x = (const float*)d_in[0];
  const int* src = (const int*)d_in[1];
  const int* dst = (const int*)d_in[2];
  const float* wn1 = (const float*)d_in[3];
  const float* ws1 = (const float*)d_in[4];
  const float* b1 = (const float*)d_in[5];
  const float* wn2 = (const float*)d_in[6];
  const float* ws2 = (const float*)d_in[7];
  const float* b2 = (const float*)d_in[8];
  float* out = (float*)d_out;

  // xn1 (fp16, 3.2MB) lives in d_out (consumed by k_gather1 before
  // k_gout writes d_out).
  __half* xn1h = (__half*)out;

  // ws layout (floats), 13.2 MB total (identical byte footprint):
  //   [0, 100000)              A: CSR end offsets (int)
  //   [100000, 100391)         starts (int)
  //   [100391, 100782)         counts (int)
  //   [102400, 102400+E)       P: packed pairs -> srclist in place (int)
  //   [1702400, 2502400)       y1 (fp16, NH halves)
  //   [2502400, 3302400)       h  (fp16, NH halves)
  //   pc (int[256*391] = 400 KB) OVERLAYS the h region: pc is dead after
  //   k_fill_proj; h is first written by k_gather1 (two kernels later).
  float* wsp = (float*)d_ws;
  int* A = (int*)wsp;
  int* starts = (int*)wsp + 100000;
  int* counts = (int*)wsp + 100391;
  int* P = (int*)(wsp + 102400);
  __half* y1h16 = (__half*)(wsp + 102400 + N_EDGES);
  __half* h16 = (__half*)(wsp + 102400 + N_EDGES + NH / 2);
  int* pc = (int*)(wsp + 102400 + N_EDGES + NH / 2);  // overlay on h16

  k_pcount<<<ABLK, 256, 0, stream>>>(dst, pc);
  k_pscan<<<1, 512, 0, stream>>>(pc, starts, counts);
  k_fill_proj<<<ABLK + PROJB, 256, 0, stream>>>(x, wn1, ws1, b1, src, dst, pc,
                                                P, xn1h, y1h16);
  k_bcsr<<<NBKT, 256, 0, stream>>>(counts, starts, P, A);
  k_gather1<<<(N_NODES + 31) / 32, 256, 0, stream>>>(xn1h, A, P, y1h16, h16);
  k_gout<<<(N_NODES + 63) / 64, 512, 0, stream>>>(h16, A, P, wn2, ws2, b2,
                                                  out);
}